// Round 7
// baseline (715.234 us; speedup 1.0000x reference)
//
#include <hip/hip_runtime.h>

#define N_NODES 100000
#define NEDGE   3200000
#define DIN     16
#define DIM     128
#define DOUT    16
#define LN_EPS  1e-5f
#define NBINS   391          // 256-target bins: bin = c >> 8
#define CHUNK   16384        // edges per chunk block
#define NPB     196          // ceil(NEDGE / CHUNK)
#define XS_STRIDE 136        // LDS bf16 row stride: 272B, 16B-aligned, 2-way-bank free
#define GGRID   1024         // GEMM grid

typedef __attribute__((ext_vector_type(8))) __bf16 bfrag_t;
typedef __attribute__((ext_vector_type(4))) float facc_t;

static __device__ __forceinline__ facc_t mfma16(bfrag_t a, bfrag_t b, facc_t c) {
    return __builtin_amdgcn_mfma_f32_16x16x32_bf16(a, b, c, 0, 0, 0);
}

// ---- bf16 helpers (RNE pack, cheap unpack) ----
static __device__ __forceinline__ unsigned f2bf(float f) {
    unsigned u = __float_as_uint(f);
    return (u + 0x7fffu + ((u >> 16) & 1u)) >> 16;
}
static __device__ __forceinline__ float bf_lo(unsigned u) { return __uint_as_float(u << 16); }
static __device__ __forceinline__ float bf_hi(unsigned u) { return __uint_as_float(u & 0xFFFF0000u); }

// ---------------- CSR build (no global per-node atomics) ----------------

__global__ __launch_bounds__(512) void k_zb(int* __restrict__ binsize) {
    if (threadIdx.x < NBINS) binsize[threadIdx.x] = 0;
}

__global__ __launch_bounds__(256) void k_hist(const int* __restrict__ col, int* __restrict__ binsize) {
    __shared__ int lh[NBINS];
    int tid = threadIdx.x;
    for (int b = tid; b < NBINS; b += 256) lh[b] = 0;
    __syncthreads();
    int e0 = blockIdx.x * CHUNK;
    int e1 = e0 + CHUNK; if (e1 > NEDGE) e1 = NEDGE;
    for (int e = e0 + tid; e < e1; e += 256)
        atomicAdd(&lh[col[e] >> 8], 1);
    __syncthreads();
    for (int b = tid; b < NBINS; b += 256)
        if (lh[b]) atomicAdd(&binsize[b], lh[b]);
}

__global__ __launch_bounds__(512) void k_scanb(const int* __restrict__ binsize,
                                               int* __restrict__ binbase, int* __restrict__ bincur) {
    __shared__ int sh[512];
    int t = threadIdx.x;
    int v = (t < NBINS) ? binsize[t] : 0;
    sh[t] = v;
    __syncthreads();
    for (int off = 1; off < 512; off <<= 1) {
        int a = (t >= off) ? sh[t - off] : 0;
        __syncthreads();
        sh[t] += a;
        __syncthreads();
    }
    if (t < NBINS) {
        int e = sh[t] - v;
        binbase[t] = e;
        bincur[t] = e;
    }
    if (t == 0) binbase[NBINS] = NEDGE;
}

__global__ __launch_bounds__(256) void k_binpass(const int* __restrict__ row, const int* __restrict__ col,
                                                 int* __restrict__ bincur, unsigned* __restrict__ pairs) {
    __shared__ int lhist[NBINS], lbase[NBINS], lofs[NBINS];
    int tid = threadIdx.x;
    for (int b = tid; b < NBINS; b += 256) { lhist[b] = 0; lofs[b] = 0; }
    __syncthreads();
    int e0 = blockIdx.x * CHUNK;
    int e1 = e0 + CHUNK; if (e1 > NEDGE) e1 = NEDGE;
    for (int e = e0 + tid; e < e1; e += 256)
        atomicAdd(&lhist[col[e] >> 8], 1);
    __syncthreads();
    for (int b = tid; b < NBINS; b += 256) {
        int h = lhist[b];
        lbase[b] = h ? atomicAdd(&bincur[b], h) : 0;
    }
    __syncthreads();
    for (int e = e0 + tid; e < e1; e += 256) {
        int c = col[e];
        int b = c >> 8;
        int pos = atomicAdd(&lofs[b], 1);
        pairs[lbase[b] + pos] = ((unsigned)(c & 255) << 17) | (unsigned)row[e];
    }
}

__global__ __launch_bounds__(256) void k_csr2(const unsigned* __restrict__ pairs,
                                              const int* __restrict__ binbase,
                                              int* __restrict__ indptr, float* __restrict__ dinv,
                                              int* __restrict__ rows_s) {
    __shared__ int lcnt[256], lptr[256], lofs[256];
    __shared__ int wsum[4];
    int tid = threadIdx.x;
    int b = blockIdx.x;
    int n0 = b << 8;
    int base = binbase[b], end = binbase[b + 1];
    lcnt[tid] = 0; lofs[tid] = 0;
    __syncthreads();
    for (int s = base + tid; s < end; s += 256)
        atomicAdd(&lcnt[pairs[s] >> 17], 1);
    __syncthreads();
    int v = lcnt[tid];
    int lane = tid & 63, w = tid >> 6;
    int s = v;
    for (int off = 1; off < 64; off <<= 1) {
        int t = __shfl_up(s, off);
        if (lane >= off) s += t;
    }
    if (lane == 63) wsum[w] = s;
    __syncthreads();
    int add = 0;
    for (int k = 0; k < w; k++) add += wsum[k];
    int excl = add + s - v;
    lptr[tid] = excl;
    int node = n0 + tid;
    if (node < N_NODES) {
        indptr[node] = base + excl;
        dinv[node] = rsqrtf((float)(v + 1));   // +1 self loop
    }
    if (b == NBINS - 1 && tid == 0) indptr[N_NODES] = NEDGE;
    __syncthreads();
    for (int s2 = base + tid; s2 < end; s2 += 256) {
        unsigned p = pairs[s2];
        int cl = p >> 17;
        int r  = p & 0x1FFFF;
        int dst = base + lptr[cl] + atomicAdd(&lofs[cl], 1);
        rows_s[dst] = r;
    }
}

// ---------------- MFMA helpers ----------------
template<int NC, int NT>
static __device__ __forceinline__ void load_bfrags(const float* __restrict__ W, int colbase,
                                                   int lane, bfrag_t B[NT][4]) {
    int q = lane >> 4, nn = lane & 15;
    #pragma unroll
    for (int nt = 0; nt < NT; nt++) {
        int col = colbase + 16 * nt + nn;
        #pragma unroll
        for (int kc = 0; kc < 4; kc++) {
            int k0 = 32 * kc + 8 * q;
            bfrag_t f;
            #pragma unroll
            for (int j = 0; j < 8; j++)
                f[j] = (__bf16)W[(size_t)(k0 + j) * NC + col];
            B[nt][kc] = f;
        }
    }
}

// stage 32x128 fp32 rows -> bf16 LDS tile (stride XS_STRIDE)
static __device__ __forceinline__ void stage_tile(const float* __restrict__ src_base,
                                                  short* __restrict__ xs, int tid) {
    int r = tid >> 3, s = tid & 7;
    const float4* src = (const float4*)(src_base + (size_t)r * DIM + 16 * s);
    float4 v0 = src[0], v1 = src[1], v2 = src[2], v3 = src[3];
    uint4 lo, hi;
    lo.x = f2bf(v0.x) | (f2bf(v0.y) << 16);
    lo.y = f2bf(v0.z) | (f2bf(v0.w) << 16);
    lo.z = f2bf(v1.x) | (f2bf(v1.y) << 16);
    lo.w = f2bf(v1.z) | (f2bf(v1.w) << 16);
    hi.x = f2bf(v2.x) | (f2bf(v2.y) << 16);
    hi.y = f2bf(v2.z) | (f2bf(v2.w) << 16);
    hi.z = f2bf(v3.x) | (f2bf(v3.y) << 16);
    hi.w = f2bf(v3.z) | (f2bf(v3.w) << 16);
    *(uint4*)&xs[r * XS_STRIDE + 16 * s] = lo;
    *(uint4*)&xs[r * XS_STRIDE + 16 * s + 8] = hi;
}

// MFMA conv block: ys (32 rows bf16) @ W-frags -> hs rows nb..nb+31, scaled by dinv
static __device__ __forceinline__ void conv_tail(const short* __restrict__ ys, bfrag_t B[2][4],
                                                 const float* __restrict__ dinv, int nb,
                                                 int lane, int wv, unsigned short* __restrict__ hs_out) {
    int q = lane >> 4, nn = lane & 15;
    facc_t a2[2][2] = {};
    #pragma unroll
    for (int kc = 0; kc < 4; kc++) {
        bfrag_t a0 = *(const bfrag_t*)&ys[nn * XS_STRIDE + 32 * kc + 8 * q];
        bfrag_t a1 = *(const bfrag_t*)&ys[(16 + nn) * XS_STRIDE + 32 * kc + 8 * q];
        a2[0][0] = mfma16(a0, B[0][kc], a2[0][0]);
        a2[0][1] = mfma16(a0, B[1][kc], a2[0][1]);
        a2[1][0] = mfma16(a1, B[0][kc], a2[1][0]);
        a2[1][1] = mfma16(a1, B[1][kc], a2[1][1]);
    }
    #pragma unroll
    for (int mt = 0; mt < 2; mt++)
        #pragma unroll
        for (int r = 0; r < 4; r++) {
            int node = nb + 16 * mt + 4 * q + r;
            float d = dinv[node];
            #pragma unroll
            for (int nt = 0; nt < 2; nt++)
                hs_out[(size_t)node * DIM + 32 * wv + 16 * nt + nn] =
                    (unsigned short)f2bf(a2[mt][nt][r] * d);
        }
}

// ---------------- encoder (fused): x = relu(X@W0+b0)@W1+b1 ; hs = (x@Wc)*dinv ----------------

__global__ __launch_bounds__(256) void k_encC(const float* __restrict__ X,
                                              const float* __restrict__ W0, const float* __restrict__ b0,
                                              const float* __restrict__ W1, const float* __restrict__ b1,
                                              const float* __restrict__ Wc, const float* __restrict__ dinv,
                                              float* __restrict__ xo, unsigned short* __restrict__ hs_out) {
    __shared__ short xs[32 * XS_STRIDE];
    __shared__ float W0s[DIN * DIM];   // 8 KB
    __shared__ float b0s[DIM];
    int tid = threadIdx.x, lane = tid & 63, wv = tid >> 6;
    for (int i = tid; i < DIN * DIM / 4; i += 256) ((float4*)W0s)[i] = ((const float4*)W0)[i];
    if (tid < DIM) b0s[tid] = b0[tid];
    bfrag_t B[2][4];
    load_bfrags<DIM, 2>(W1, 32 * wv, lane, B);
    bfrag_t Bc[2][4];
    load_bfrags<DIM, 2>(Wc, 32 * wv, lane, Bc);
    int q = lane >> 4, nn = lane & 15;
    float bias[2] = { b1[32 * wv + nn], b1[32 * wv + 16 + nn] };
    const int ngroups = N_NODES / 32;
    for (int g = blockIdx.x; g < ngroups; g += gridDim.x) {
        int n0 = g * 32;
        __syncthreads();
        {   // stage: t = relu(X@W0+b0), node r, cols 16s..16s+15 -> bf16 LDS
            int r = tid >> 3, s = tid & 7;
            float xr[DIN];
            const float4* xsrc = (const float4*)(X + (size_t)(n0 + r) * DIN);
            #pragma unroll
            for (int i = 0; i < 4; i++) {
                float4 v = xsrc[i];
                xr[4*i] = v.x; xr[4*i+1] = v.y; xr[4*i+2] = v.z; xr[4*i+3] = v.w;
            }
            unsigned pk[8];
            #pragma unroll
            for (int cc = 0; cc < 16; cc += 2) {
                int c0 = 16 * s + cc;
                float a0 = b0s[c0], a1 = b0s[c0 + 1];
                #pragma unroll
                for (int k = 0; k < DIN; k++) {
                    float2 w = *(const float2*)&W0s[k * DIM + c0];
                    a0 += xr[k] * w.x; a1 += xr[k] * w.y;
                }
                pk[cc >> 1] = f2bf(fmaxf(a0, 0.f)) | (f2bf(fmaxf(a1, 0.f)) << 16);
            }
            *(uint4*)&xs[r * XS_STRIDE + 16 * s] = *(uint4*)&pk[0];
            *(uint4*)&xs[r * XS_STRIDE + 16 * s + 8] = *(uint4*)&pk[4];
        }
        __syncthreads();
        facc_t acc[2][2];
        #pragma unroll
        for (int mt = 0; mt < 2; mt++)
            #pragma unroll
            for (int nt = 0; nt < 2; nt++)
                acc[mt][nt] = (facc_t){bias[nt], bias[nt], bias[nt], bias[nt]};
        #pragma unroll
        for (int kc = 0; kc < 4; kc++) {
            bfrag_t a0 = *(const bfrag_t*)&xs[nn * XS_STRIDE + 32 * kc + 8 * q];
            bfrag_t a1 = *(const bfrag_t*)&xs[(16 + nn) * XS_STRIDE + 32 * kc + 8 * q];
            acc[0][0] = mfma16(a0, B[0][kc], acc[0][0]);
            acc[0][1] = mfma16(a0, B[1][kc], acc[0][1]);
            acc[1][0] = mfma16(a1, B[0][kc], acc[1][0]);
            acc[1][1] = mfma16(a1, B[1][kc], acc[1][1]);
        }
        // write x (fp32) and re-stage x tile as bf16 for the fused conv
        __syncthreads();   // all A-reads done; xs can be overwritten
        #pragma unroll
        for (int mt = 0; mt < 2; mt++)
            #pragma unroll
            for (int r = 0; r < 4; r++) {
                int node = n0 + 16 * mt + 4 * q + r;
                int nl = 16 * mt + 4 * q + r;
                #pragma unroll
                for (int nt = 0; nt < 2; nt++) {
                    float fv = acc[mt][nt][r];
                    xo[(size_t)node * DIM + 32 * wv + 16 * nt + nn] = fv;
                    xs[nl * XS_STRIDE + 32 * wv + 16 * nt + nn] = (short)f2bf(fv);
                }
            }
        __syncthreads();
        conv_tail(xs, Bc, dinv, n0, lane, wv, hs_out);
    }
}

// ---------------- fused gather + residual + bias + LayerNorm (+ next-step conv) ----------------
// 32 nodes/block, 8 nodes/wave sequential. dwordx4 gather (16 lanes = one 256B hs row,
// 4 edges per load). After LN: y -> LDS bf16 tile; if DO_CONV, block MFMA -> hs_out.

template<bool DO_CONV>
__global__ __launch_bounds__(256) void k_aggM(const uint4* __restrict__ hs4, float* __restrict__ x,
                                              const float* __restrict__ dinv,
                                              const int* __restrict__ indptr,
                                              const int* __restrict__ rows_s,
                                              const float* __restrict__ bconv,
                                              const float* __restrict__ g_, const float* __restrict__ b_,
                                              const float* __restrict__ W,
                                              unsigned short* __restrict__ hs_out) {
    __shared__ short ys[32 * XS_STRIDE];
    int tid = threadIdx.x, lane = tid & 63, wv = tid >> 6;
    bfrag_t B[2][4];
    if constexpr (DO_CONV) load_bfrags<DIM, 2>(W, 32 * wv, lane, B);
    int sub = lane >> 4, part = lane & 15;
    int nb = blockIdx.x * 32;
    // invariant per-lane vectors
    const float4* bc4 = (const float4*)(bconv + 8 * part);
    float4 bcv0 = bc4[0], bcv1 = bc4[1];
    const float4* gp = (const float4*)(g_ + 8 * part);
    const float4* bp = (const float4*)(b_ + 8 * part);
    float4 g0 = gp[0], g1 = gp[1];
    float4 bb0 = bp[0], bb1 = bp[1];
    #pragma unroll 1
    for (int i = 0; i < 8; i++) {
        int v = nb + 8 * wv + i;
        float acc[8];
        {   // self loop: count once (sub 0 only; others init 0)
            uint4 u = hs4[(size_t)v * 16 + part];
            float sel = (sub == 0) ? 1.f : 0.f;
            acc[0] = sel * bf_lo(u.x); acc[1] = sel * bf_hi(u.x);
            acc[2] = sel * bf_lo(u.y); acc[3] = sel * bf_hi(u.y);
            acc[4] = sel * bf_lo(u.z); acc[5] = sel * bf_hi(u.z);
            acc[6] = sel * bf_lo(u.w); acc[7] = sel * bf_hi(u.w);
        }
        int beg = indptr[v], end = indptr[v + 1];
        for (int base = beg; base < end; base += 64) {
            int m = end - base; if (m > 64) m = 64;
            int r0 = rows_s[base + (lane < m ? lane : m - 1)];
            int k = 0;
            for (; k + 8 <= m; k += 8) {          // 2 loads in flight, 8 edges/iter
                int ra = __shfl(r0, k + sub);
                int rb = __shfl(r0, k + 4 + sub);
                uint4 ua = hs4[(size_t)ra * 16 + part];
                uint4 ub = hs4[(size_t)rb * 16 + part];
                acc[0] += bf_lo(ua.x); acc[1] += bf_hi(ua.x);
                acc[2] += bf_lo(ua.y); acc[3] += bf_hi(ua.y);
                acc[4] += bf_lo(ua.z); acc[5] += bf_hi(ua.z);
                acc[6] += bf_lo(ua.w); acc[7] += bf_hi(ua.w);
                acc[0] += bf_lo(ub.x); acc[1] += bf_hi(ub.x);
                acc[2] += bf_lo(ub.y); acc[3] += bf_hi(ub.y);
                acc[4] += bf_lo(ub.z); acc[5] += bf_hi(ub.z);
                acc[6] += bf_lo(ub.w); acc[7] += bf_hi(ub.w);
            }
            for (; k < m; k += 4) {               // predicated tail group
                int idx = k + sub;
                bool valid = idx < m;
                int r = __shfl(r0, valid ? idx : m - 1);
                uint4 u = hs4[(size_t)r * 16 + part];
                if (valid) {
                    acc[0] += bf_lo(u.x); acc[1] += bf_hi(u.x);
                    acc[2] += bf_lo(u.y); acc[3] += bf_hi(u.y);
                    acc[4] += bf_lo(u.z); acc[5] += bf_hi(u.z);
                    acc[6] += bf_lo(u.w); acc[7] += bf_hi(u.w);
                }
            }
        }
        #pragma unroll
        for (int j = 0; j < 8; j++) {             // sum the 4 sub-copies
            acc[j] += __shfl_xor(acc[j], 16);
            acc[j] += __shfl_xor(acc[j], 32);
        }
        float dv = dinv[v];
        float y[8];
        {
            const float4* xr = (const float4*)(x + (size_t)v * DIM + 8 * part);
            float4 x0 = xr[0], x1 = xr[1];
            y[0] = x0.x + dv * acc[0] + bcv0.x; y[1] = x0.y + dv * acc[1] + bcv0.y;
            y[2] = x0.z + dv * acc[2] + bcv0.z; y[3] = x0.w + dv * acc[3] + bcv0.w;
            y[4] = x1.x + dv * acc[4] + bcv1.x; y[5] = x1.y + dv * acc[5] + bcv1.y;
            y[6] = x1.z + dv * acc[6] + bcv1.z; y[7] = x1.w + dv * acc[7] + bcv1.w;
        }
        float s = 0.f, s2 = 0.f;
        #pragma unroll
        for (int j = 0; j < 8; j++) { s += y[j]; s2 += y[j] * y[j]; }
        #pragma unroll
        for (int off = 1; off < 16; off <<= 1) {
            s += __shfl_xor(s, off);
            s2 += __shfl_xor(s2, off);
        }
        float mu = s * (1.f / 128.f);
        float rstd = rsqrtf(s2 * (1.f / 128.f) - mu * mu + LN_EPS);
        if (sub == 0) {
            float o[8];
            o[0] = (y[0] - mu) * rstd * g0.x + bb0.x;
            o[1] = (y[1] - mu) * rstd * g0.y + bb0.y;
            o[2] = (y[2] - mu) * rstd * g0.z + bb0.z;
            o[3] = (y[3] - mu) * rstd * g0.w + bb0.w;
            o[4] = (y[4] - mu) * rstd * g1.x + bb1.x;
            o[5] = (y[5] - mu) * rstd * g1.y + bb1.y;
            o[6] = (y[6] - mu) * rstd * g1.z + bb1.z;
            o[7] = (y[7] - mu) * rstd * g1.w + bb1.w;
            float4* xw = (float4*)(x + (size_t)v * DIM + 8 * part);
            xw[0] = make_float4(o[0], o[1], o[2], o[3]);
            xw[1] = make_float4(o[4], o[5], o[6], o[7]);
            if constexpr (DO_CONV) {
                uint4 pk;
                pk.x = f2bf(o[0]) | (f2bf(o[1]) << 16);
                pk.y = f2bf(o[2]) | (f2bf(o[3]) << 16);
                pk.z = f2bf(o[4]) | (f2bf(o[5]) << 16);
                pk.w = f2bf(o[6]) | (f2bf(o[7]) << 16);
                *(uint4*)&ys[(8 * wv + i) * XS_STRIDE + 8 * part] = pk;
            }
        }
    }
    if constexpr (DO_CONV) {
        __syncthreads();
        conv_tail(ys, B, dinv, nb, lane, wv, hs_out);
    }
}

// ---------------- decoder (fused): out = relu(x@W0+b0)@W1 + b1 ----------------

__global__ __launch_bounds__(256) void k_decM(const float* __restrict__ xi,
                                              const float* __restrict__ W0, const float* __restrict__ b0f,
                                              const float* __restrict__ W1, const float* __restrict__ b1f,
                                              float* __restrict__ out) {
    __shared__ short xs[32 * XS_STRIDE];
    int tid = threadIdx.x, lane = tid & 63, wv = tid >> 6;
    bfrag_t B0[2][4];
    load_bfrags<DIM, 2>(W0, 32 * wv, lane, B0);
    int q = lane >> 4, nn = lane & 15;
    bfrag_t B1[4];
    #pragma unroll
    for (int kc = 0; kc < 4; kc++) {
        int k0 = 32 * kc + 8 * q;
        bfrag_t f;
        #pragma unroll
        for (int j = 0; j < 8; j++)
            f[j] = (__bf16)W1[(size_t)(k0 + j) * DOUT + nn];
        B1[kc] = f;
    }
    float bias0[2] = { b0f[32 * wv + nn], b0f[32 * wv + 16 + nn] };
    float bias1 = b1f[nn];
    const int ngroups = N_NODES / 32;
    for (int g = blockIdx.x; g < ngroups; g += gridDim.x) {
        int n0 = g * 32;
        __syncthreads();
        stage_tile(xi + (size_t)n0 * DIM, xs, tid);
        __syncthreads();
        facc_t acc[2][2];
        #pragma unroll
        for (int mt = 0; mt < 2; mt++)
            #pragma unroll
            for (int nt = 0; nt < 2; nt++)
                acc[mt][nt] = (facc_t){bias0[nt], bias0[nt], bias0[nt], bias0[nt]};
        #pragma unroll
        for (int kc = 0; kc < 4; kc++) {
            bfrag_t a0 = *(const bfrag_t*)&xs[nn * XS_STRIDE + 32 * kc + 8 * q];
            bfrag_t a1 = *(const bfrag_t*)&xs[(16 + nn) * XS_STRIDE + 32 * kc + 8 * q];
            acc[0][0] = mfma16(a0, B0[0][kc], acc[0][0]);
            acc[0][1] = mfma16(a0, B0[1][kc], acc[0][1]);
            acc[1][0] = mfma16(a1, B0[0][kc], acc[1][0]);
            acc[1][1] = mfma16(a1, B0[1][kc], acc[1][1]);
        }
        __syncthreads();   // all A-reads of x-tile done; xs can be overwritten
        #pragma unroll
        for (int mt = 0; mt < 2; mt++)
            #pragma unroll
            for (int nt = 0; nt < 2; nt++)
                #pragma unroll
                for (int r = 0; r < 4; r++) {
                    int nl = 16 * mt + 4 * q + r;
                    int col = 32 * wv + 16 * nt + nn;
                    xs[nl * XS_STRIDE + col] = (short)f2bf(fmaxf(acc[mt][nt][r], 0.f));
                }
        __syncthreads();
        if (wv < 2) {   // waves 0,1: t2[32x128] @ W1[128x16]
            facc_t acc2 = (facc_t){bias1, bias1, bias1, bias1};
            #pragma unroll
            for (int kc = 0; kc < 4; kc++) {
                bfrag_t a = *(const bfrag_t*)&xs[(16 * wv + nn) * XS_STRIDE + 32 * kc + 8 * q];
                acc2 = mfma16(a, B1[kc], acc2);
            }
            #pragma unroll
            for (int r = 0; r < 4; r++) {
                int node = n0 + 16 * wv + 4 * q + r;
                out[(size_t)node * DOUT + nn] = acc2[r];
            }
        }
    }
}

// ---------------- launch ----------------

extern "C" void kernel_launch(void* const* d_in, const int* in_sizes, int n_in,
                              void* d_out, int out_size, void* d_ws, size_t ws_size,
                              hipStream_t stream) {
    const float* X      = (const float*)d_in[0];
    const float* W_enc0 = (const float*)d_in[1];
    const float* b_enc0 = (const float*)d_in[2];
    const float* W_enc1 = (const float*)d_in[3];
    const float* b_enc1 = (const float*)d_in[4];
    const float* W_conv = (const float*)d_in[5];
    const float* b_conv = (const float*)d_in[6];
    const float* ln_g   = (const float*)d_in[7];
    const float* ln_b   = (const float*)d_in[8];
    const float* W_dec0 = (const float*)d_in[9];
    const float* b_dec0 = (const float*)d_in[10];
    const float* W_dec1 = (const float*)d_in[11];
    const float* b_dec1 = (const float*)d_in[12];
    const int*   erow   = (const int*)d_in[13];         // edge_index[0] = sources
    const int*   ecol   = erow + NEDGE;                 // edge_index[1] = targets
    float* out = (float*)d_out;

    float*          x       = (float*)d_ws;                                  // N*128 f32
    unsigned short* hs_a    = (unsigned short*)(x + (size_t)N_NODES * DIM);  // N*128 bf16
    unsigned short* hs_b    = hs_a + (size_t)N_NODES * DIM;                  // N*128 bf16
    float*          dinv    = (float*)(hs_b + (size_t)N_NODES * DIM);        // N f32
    int*            indptr  = (int*)(dinv + N_NODES);                        // N+1 int
    int*            binsize = indptr + N_NODES + 8;                          // NBINS
    int*            binbase = binsize + NBINS + 8;                           // NBINS+1
    int*            bincur  = binbase + NBINS + 9;                           // NBINS
    int*            rows_s  = bincur + NBINS + 8;                            // E int
    unsigned*       pairs   = (unsigned*)hs_a;  // overlay: consumed before enc writes hs_a

    // CSR build (per launch; d_ws is re-poisoned before every call)
    k_zb     <<<1, 512, 0, stream>>>(binsize);
    k_hist   <<<NPB, 256, 0, stream>>>(ecol, binsize);
    k_scanb  <<<1, 512, 0, stream>>>(binsize, binbase, bincur);
    k_binpass<<<NPB, 256, 0, stream>>>(erow, ecol, bincur, pairs);
    k_csr2   <<<NBINS, 256, 0, stream>>>(pairs, binbase, indptr, dinv, rows_s);

    // encoder + conv step 1 fused
    k_encC<<<GGRID, 256, 0, stream>>>(X, W_enc0, b_enc0, W_enc1, b_enc1, W_conv, dinv, x, hs_a);

    // msg steps: agg(+LN) fused with next step's conv (double-buffered hs)
    k_aggM<true> <<<N_NODES / 32, 256, 0, stream>>>((const uint4*)hs_a, x, dinv, indptr, rows_s,
                                                    b_conv, ln_g, ln_b, W_conv, hs_b);
    k_aggM<true> <<<N_NODES / 32, 256, 0, stream>>>((const uint4*)hs_b, x, dinv, indptr, rows_s,
                                                    b_conv, ln_g, ln_b, W_conv, hs_a);
    k_aggM<false><<<N_NODES / 32, 256, 0, stream>>>((const uint4*)hs_a, x, dinv, indptr, rows_s,
                                                    b_conv, ln_g, ln_b, nullptr, nullptr);

    k_decM<<<GGRID, 256, 0, stream>>>(x, W_dec0, b_dec0, W_dec1, b_dec1, out);
}

// Round 8
// 639.916 us; speedup vs baseline: 1.1177x; 1.1177x over previous
//
#include <hip/hip_runtime.h>

#define N_NODES 100000
#define NEDGE   3200000
#define DIN     16
#define DIM     128
#define DOUT    16
#define LN_EPS  1e-5f
#define NBINS   391          // 256-target bins: bin = c >> 8
#define CHUNK   16384        // edges per chunk block
#define NPB     196          // ceil(NEDGE / CHUNK)
#define XS_STRIDE 136        // LDS bf16 row stride: 272B, 16B-aligned, 2-way-bank free
#define GGRID   1024         // GEMM grid

typedef __attribute__((ext_vector_type(8))) __bf16 bfrag_t;
typedef __attribute__((ext_vector_type(4))) float facc_t;

static __device__ __forceinline__ facc_t mfma16(bfrag_t a, bfrag_t b, facc_t c) {
    return __builtin_amdgcn_mfma_f32_16x16x32_bf16(a, b, c, 0, 0, 0);
}

// ---- bf16 helpers (RNE pack, cheap unpack) ----
static __device__ __forceinline__ unsigned f2bf(float f) {
    unsigned u = __float_as_uint(f);
    return (u + 0x7fffu + ((u >> 16) & 1u)) >> 16;
}
static __device__ __forceinline__ float bf_lo(unsigned u) { return __uint_as_float(u << 16); }
static __device__ __forceinline__ float bf_hi(unsigned u) { return __uint_as_float(u & 0xFFFF0000u); }

// ---------------- CSR build (no global per-node atomics) ----------------

__global__ __launch_bounds__(512) void k_zb(int* __restrict__ binsize) {
    if (threadIdx.x < NBINS) binsize[threadIdx.x] = 0;
}

__global__ __launch_bounds__(256) void k_hist(const int* __restrict__ col, int* __restrict__ binsize) {
    __shared__ int lh[NBINS];
    int tid = threadIdx.x;
    for (int b = tid; b < NBINS; b += 256) lh[b] = 0;
    __syncthreads();
    int e0 = blockIdx.x * CHUNK;
    int e1 = e0 + CHUNK; if (e1 > NEDGE) e1 = NEDGE;
    for (int e = e0 + tid; e < e1; e += 256)
        atomicAdd(&lh[col[e] >> 8], 1);
    __syncthreads();
    for (int b = tid; b < NBINS; b += 256)
        if (lh[b]) atomicAdd(&binsize[b], lh[b]);
}

__global__ __launch_bounds__(512) void k_scanb(const int* __restrict__ binsize,
                                               int* __restrict__ binbase, int* __restrict__ bincur) {
    __shared__ int sh[512];
    int t = threadIdx.x;
    int v = (t < NBINS) ? binsize[t] : 0;
    sh[t] = v;
    __syncthreads();
    for (int off = 1; off < 512; off <<= 1) {
        int a = (t >= off) ? sh[t - off] : 0;
        __syncthreads();
        sh[t] += a;
        __syncthreads();
    }
    if (t < NBINS) {
        int e = sh[t] - v;
        binbase[t] = e;
        bincur[t] = e;
    }
    if (t == 0) binbase[NBINS] = NEDGE;
}

__global__ __launch_bounds__(256) void k_binpass(const int* __restrict__ row, const int* __restrict__ col,
                                                 int* __restrict__ bincur, unsigned* __restrict__ pairs) {
    __shared__ int lhist[NBINS], lbase[NBINS], lofs[NBINS];
    int tid = threadIdx.x;
    for (int b = tid; b < NBINS; b += 256) { lhist[b] = 0; lofs[b] = 0; }
    __syncthreads();
    int e0 = blockIdx.x * CHUNK;
    int e1 = e0 + CHUNK; if (e1 > NEDGE) e1 = NEDGE;
    for (int e = e0 + tid; e < e1; e += 256)
        atomicAdd(&lhist[col[e] >> 8], 1);
    __syncthreads();
    for (int b = tid; b < NBINS; b += 256) {
        int h = lhist[b];
        lbase[b] = h ? atomicAdd(&bincur[b], h) : 0;
    }
    __syncthreads();
    for (int e = e0 + tid; e < e1; e += 256) {
        int c = col[e];
        int b = c >> 8;
        int pos = atomicAdd(&lofs[b], 1);
        pairs[lbase[b] + pos] = ((unsigned)(c & 255) << 17) | (unsigned)row[e];
    }
}

__global__ __launch_bounds__(256) void k_csr2(const unsigned* __restrict__ pairs,
                                              const int* __restrict__ binbase,
                                              int* __restrict__ indptr, float* __restrict__ dinv,
                                              int* __restrict__ rows_s) {
    __shared__ int lcnt[256], lptr[256], lofs[256];
    __shared__ int wsum[4];
    int tid = threadIdx.x;
    int b = blockIdx.x;
    int n0 = b << 8;
    int base = binbase[b], end = binbase[b + 1];
    lcnt[tid] = 0; lofs[tid] = 0;
    __syncthreads();
    for (int s = base + tid; s < end; s += 256)
        atomicAdd(&lcnt[pairs[s] >> 17], 1);
    __syncthreads();
    int v = lcnt[tid];
    int lane = tid & 63, w = tid >> 6;
    int s = v;
    for (int off = 1; off < 64; off <<= 1) {
        int t = __shfl_up(s, off);
        if (lane >= off) s += t;
    }
    if (lane == 63) wsum[w] = s;
    __syncthreads();
    int add = 0;
    for (int k = 0; k < w; k++) add += wsum[k];
    int excl = add + s - v;
    lptr[tid] = excl;
    int node = n0 + tid;
    if (node < N_NODES) {
        indptr[node] = base + excl;
        dinv[node] = rsqrtf((float)(v + 1));   // +1 self loop
    }
    if (b == NBINS - 1 && tid == 0) indptr[N_NODES] = NEDGE;
    __syncthreads();
    for (int s2 = base + tid; s2 < end; s2 += 256) {
        unsigned p = pairs[s2];
        int cl = p >> 17;
        int r  = p & 0x1FFFF;
        int dst = base + lptr[cl] + atomicAdd(&lofs[cl], 1);
        rows_s[dst] = r;
    }
}

// ---------------- MFMA helpers ----------------
template<int NC, int NT>
static __device__ __forceinline__ void load_bfrags(const float* __restrict__ W, int colbase,
                                                   int lane, bfrag_t B[NT][4]) {
    int q = lane >> 4, nn = lane & 15;
    #pragma unroll
    for (int nt = 0; nt < NT; nt++) {
        int col = colbase + 16 * nt + nn;
        #pragma unroll
        for (int kc = 0; kc < 4; kc++) {
            int k0 = 32 * kc + 8 * q;
            bfrag_t f;
            #pragma unroll
            for (int j = 0; j < 8; j++)
                f[j] = (__bf16)W[(size_t)(k0 + j) * NC + col];
            B[nt][kc] = f;
        }
    }
}

// stage 32x128 fp32 rows -> bf16 LDS tile (stride XS_STRIDE)
static __device__ __forceinline__ void stage_tile(const float* __restrict__ src_base,
                                                  short* __restrict__ xs, int tid) {
    int r = tid >> 3, s = tid & 7;
    const float4* src = (const float4*)(src_base + (size_t)r * DIM + 16 * s);
    float4 v0 = src[0], v1 = src[1], v2 = src[2], v3 = src[3];
    uint4 lo, hi;
    lo.x = f2bf(v0.x) | (f2bf(v0.y) << 16);
    lo.y = f2bf(v0.z) | (f2bf(v0.w) << 16);
    lo.z = f2bf(v1.x) | (f2bf(v1.y) << 16);
    lo.w = f2bf(v1.z) | (f2bf(v1.w) << 16);
    hi.x = f2bf(v2.x) | (f2bf(v2.y) << 16);
    hi.y = f2bf(v2.z) | (f2bf(v2.w) << 16);
    hi.z = f2bf(v3.x) | (f2bf(v3.y) << 16);
    hi.w = f2bf(v3.z) | (f2bf(v3.w) << 16);
    *(uint4*)&xs[r * XS_STRIDE + 16 * s] = lo;
    *(uint4*)&xs[r * XS_STRIDE + 16 * s + 8] = hi;
}

// MFMA conv block: ys (32 rows bf16 in LDS) @ W-frags -> hs rows nb..nb+31, scaled by dinv
static __device__ __forceinline__ void conv_tail(const short* __restrict__ ys, bfrag_t B[2][4],
                                                 const float* __restrict__ dinv, int nb,
                                                 int lane, int wv, unsigned short* __restrict__ hs_out) {
    int q = lane >> 4, nn = lane & 15;
    facc_t a2[2][2] = {};
    #pragma unroll
    for (int kc = 0; kc < 4; kc++) {
        bfrag_t a0 = *(const bfrag_t*)&ys[nn * XS_STRIDE + 32 * kc + 8 * q];
        bfrag_t a1 = *(const bfrag_t*)&ys[(16 + nn) * XS_STRIDE + 32 * kc + 8 * q];
        a2[0][0] = mfma16(a0, B[0][kc], a2[0][0]);
        a2[0][1] = mfma16(a0, B[1][kc], a2[0][1]);
        a2[1][0] = mfma16(a1, B[0][kc], a2[1][0]);
        a2[1][1] = mfma16(a1, B[1][kc], a2[1][1]);
    }
    #pragma unroll
    for (int mt = 0; mt < 2; mt++)
        #pragma unroll
        for (int r = 0; r < 4; r++) {
            int node = nb + 16 * mt + 4 * q + r;
            float d = dinv[node];
            #pragma unroll
            for (int nt = 0; nt < 2; nt++)
                hs_out[(size_t)node * DIM + 32 * wv + 16 * nt + nn] =
                    (unsigned short)f2bf(a2[mt][nt][r] * d);
        }
}

// ---------------- encoder (fused): x = relu(X@W0+b0)@W1+b1 ; hs = (x@Wc)*dinv ----------------

__global__ __launch_bounds__(256) void k_encC(const float* __restrict__ X,
                                              const float* __restrict__ W0, const float* __restrict__ b0,
                                              const float* __restrict__ W1, const float* __restrict__ b1,
                                              const float* __restrict__ Wc, const float* __restrict__ dinv,
                                              float* __restrict__ xo, unsigned short* __restrict__ hs_out) {
    __shared__ short xs[32 * XS_STRIDE];
    __shared__ float W0s[DIN * DIM];   // 8 KB
    __shared__ float b0s[DIM];
    int tid = threadIdx.x, lane = tid & 63, wv = tid >> 6;
    for (int i = tid; i < DIN * DIM / 4; i += 256) ((float4*)W0s)[i] = ((const float4*)W0)[i];
    if (tid < DIM) b0s[tid] = b0[tid];
    bfrag_t B[2][4];
    load_bfrags<DIM, 2>(W1, 32 * wv, lane, B);
    bfrag_t Bc[2][4];
    load_bfrags<DIM, 2>(Wc, 32 * wv, lane, Bc);
    int q = lane >> 4, nn = lane & 15;
    float bias[2] = { b1[32 * wv + nn], b1[32 * wv + 16 + nn] };
    const int ngroups = N_NODES / 32;
    for (int g = blockIdx.x; g < ngroups; g += gridDim.x) {
        int n0 = g * 32;
        __syncthreads();
        {   // stage: t = relu(X@W0+b0), node r, cols 16s..16s+15 -> bf16 LDS
            int r = tid >> 3, s = tid & 7;
            float xr[DIN];
            const float4* xsrc = (const float4*)(X + (size_t)(n0 + r) * DIN);
            #pragma unroll
            for (int i = 0; i < 4; i++) {
                float4 v = xsrc[i];
                xr[4*i] = v.x; xr[4*i+1] = v.y; xr[4*i+2] = v.z; xr[4*i+3] = v.w;
            }
            unsigned pk[8];
            #pragma unroll
            for (int cc = 0; cc < 16; cc += 2) {
                int c0 = 16 * s + cc;
                float a0 = b0s[c0], a1 = b0s[c0 + 1];
                #pragma unroll
                for (int k = 0; k < DIN; k++) {
                    float2 w = *(const float2*)&W0s[k * DIM + c0];
                    a0 += xr[k] * w.x; a1 += xr[k] * w.y;
                }
                pk[cc >> 1] = f2bf(fmaxf(a0, 0.f)) | (f2bf(fmaxf(a1, 0.f)) << 16);
            }
            *(uint4*)&xs[r * XS_STRIDE + 16 * s] = *(uint4*)&pk[0];
            *(uint4*)&xs[r * XS_STRIDE + 16 * s + 8] = *(uint4*)&pk[4];
        }
        __syncthreads();
        facc_t acc[2][2];
        #pragma unroll
        for (int mt = 0; mt < 2; mt++)
            #pragma unroll
            for (int nt = 0; nt < 2; nt++)
                acc[mt][nt] = (facc_t){bias[nt], bias[nt], bias[nt], bias[nt]};
        #pragma unroll
        for (int kc = 0; kc < 4; kc++) {
            bfrag_t a0 = *(const bfrag_t*)&xs[nn * XS_STRIDE + 32 * kc + 8 * q];
            bfrag_t a1 = *(const bfrag_t*)&xs[(16 + nn) * XS_STRIDE + 32 * kc + 8 * q];
            acc[0][0] = mfma16(a0, B[0][kc], acc[0][0]);
            acc[0][1] = mfma16(a0, B[1][kc], acc[0][1]);
            acc[1][0] = mfma16(a1, B[0][kc], acc[1][0]);
            acc[1][1] = mfma16(a1, B[1][kc], acc[1][1]);
        }
        // write x (fp32) and re-stage x tile as bf16 for the fused conv
        __syncthreads();   // all A-reads done; xs can be overwritten
        #pragma unroll
        for (int mt = 0; mt < 2; mt++)
            #pragma unroll
            for (int r = 0; r < 4; r++) {
                int node = n0 + 16 * mt + 4 * q + r;
                int nl = 16 * mt + 4 * q + r;
                #pragma unroll
                for (int nt = 0; nt < 2; nt++) {
                    float fv = acc[mt][nt][r];
                    xo[(size_t)node * DIM + 32 * wv + 16 * nt + nn] = fv;
                    xs[nl * XS_STRIDE + 32 * wv + 16 * nt + nn] = (short)f2bf(fv);
                }
            }
        __syncthreads();
        conv_tail(xs, Bc, dinv, n0, lane, wv, hs_out);
    }
}

// ---------------- conv: hs_bf16 = (x @ W_conv) * dinv[node] ----------------

__global__ __launch_bounds__(256) void k_convM(const float* __restrict__ xi,
                                               const float* __restrict__ W,
                                               const float* __restrict__ dinv,
                                               unsigned short* __restrict__ hs) {
    __shared__ short xs[32 * XS_STRIDE];
    int tid = threadIdx.x, lane = tid & 63, wv = tid >> 6;
    bfrag_t B[2][4];
    load_bfrags<DIM, 2>(W, 32 * wv, lane, B);
    const int ngroups = N_NODES / 32;
    for (int g = blockIdx.x; g < ngroups; g += gridDim.x) {
        int n0 = g * 32;
        __syncthreads();
        stage_tile(xi + (size_t)n0 * DIM, xs, tid);
        __syncthreads();
        conv_tail(xs, B, dinv, n0, lane, wv, hs);
    }
}

// ---------------- fused gather + residual + bias + LayerNorm ----------------
// one wave per node (VGPR-lean, max occupancy). dwordx4 gather: 16 lanes cover one
// 256B hs row => one load gathers 4 edges. sub = edge-in-group, part = 16B chunk.

__global__ __launch_bounds__(256) void k_agg_ln(const uint4* __restrict__ hs4, float* __restrict__ x,
                                                const float* __restrict__ dinv,
                                                const int* __restrict__ indptr,
                                                const int* __restrict__ rows_s,
                                                const float* __restrict__ bconv,
                                                const float* __restrict__ g_, const float* __restrict__ b_) {
    int v = (blockIdx.x * blockDim.x + threadIdx.x) >> 6;
    int lane = threadIdx.x & 63;
    if (v >= N_NODES) return;
    int sub = lane >> 4, part = lane & 15;
    float acc[8];
    {   // self loop: count once (sub 0 only; others init 0)
        uint4 u = hs4[(size_t)v * 16 + part];
        float sel = (sub == 0) ? 1.f : 0.f;
        acc[0] = sel * bf_lo(u.x); acc[1] = sel * bf_hi(u.x);
        acc[2] = sel * bf_lo(u.y); acc[3] = sel * bf_hi(u.y);
        acc[4] = sel * bf_lo(u.z); acc[5] = sel * bf_hi(u.z);
        acc[6] = sel * bf_lo(u.w); acc[7] = sel * bf_hi(u.w);
    }
    int beg = indptr[v], end = indptr[v + 1];
    for (int base = beg; base < end; base += 64) {
        int m = end - base; if (m > 64) m = 64;
        int r0 = rows_s[base + (lane < m ? lane : m - 1)];
        int k = 0;
        for (; k + 8 <= m; k += 8) {          // 2 loads in flight, 8 edges/iter
            int ra = __shfl(r0, k + sub);
            int rb = __shfl(r0, k + 4 + sub);
            uint4 ua = hs4[(size_t)ra * 16 + part];
            uint4 ub = hs4[(size_t)rb * 16 + part];
            acc[0] += bf_lo(ua.x); acc[1] += bf_hi(ua.x);
            acc[2] += bf_lo(ua.y); acc[3] += bf_hi(ua.y);
            acc[4] += bf_lo(ua.z); acc[5] += bf_hi(ua.z);
            acc[6] += bf_lo(ua.w); acc[7] += bf_hi(ua.w);
            acc[0] += bf_lo(ub.x); acc[1] += bf_hi(ub.x);
            acc[2] += bf_lo(ub.y); acc[3] += bf_hi(ub.y);
            acc[4] += bf_lo(ub.z); acc[5] += bf_hi(ub.z);
            acc[6] += bf_lo(ub.w); acc[7] += bf_hi(ub.w);
        }
        for (; k < m; k += 4) {               // predicated tail group
            int idx = k + sub;
            bool valid = idx < m;
            int r = __shfl(r0, valid ? idx : m - 1);
            uint4 u = hs4[(size_t)r * 16 + part];
            if (valid) {
                acc[0] += bf_lo(u.x); acc[1] += bf_hi(u.x);
                acc[2] += bf_lo(u.y); acc[3] += bf_hi(u.y);
                acc[4] += bf_lo(u.z); acc[5] += bf_hi(u.z);
                acc[6] += bf_lo(u.w); acc[7] += bf_hi(u.w);
            }
        }
    }
    #pragma unroll
    for (int j = 0; j < 8; j++) {             // sum the 4 sub-copies
        acc[j] += __shfl_xor(acc[j], 16);
        acc[j] += __shfl_xor(acc[j], 32);
    }
    float dv = dinv[v];
    float y[8];
    {
        const float4* xr = (const float4*)(x + (size_t)v * DIM + 8 * part);
        float4 x0 = xr[0], x1 = xr[1];
        const float4* bc = (const float4*)(bconv + 8 * part);
        float4 b0 = bc[0], b1 = bc[1];
        y[0] = x0.x + dv * acc[0] + b0.x; y[1] = x0.y + dv * acc[1] + b0.y;
        y[2] = x0.z + dv * acc[2] + b0.z; y[3] = x0.w + dv * acc[3] + b0.w;
        y[4] = x1.x + dv * acc[4] + b1.x; y[5] = x1.y + dv * acc[5] + b1.y;
        y[6] = x1.z + dv * acc[6] + b1.z; y[7] = x1.w + dv * acc[7] + b1.w;
    }
    float s = 0.f, s2 = 0.f;
    #pragma unroll
    for (int j = 0; j < 8; j++) { s += y[j]; s2 += y[j] * y[j]; }
    #pragma unroll
    for (int off = 1; off < 16; off <<= 1) {  // reduce within 16-lane group (covers all parts)
        s += __shfl_xor(s, off);
        s2 += __shfl_xor(s2, off);
    }
    float mu = s * (1.f / 128.f);
    float rstd = rsqrtf(s2 * (1.f / 128.f) - mu * mu + LN_EPS);
    if (sub == 0) {
        const float4* gp = (const float4*)(g_ + 8 * part);
        const float4* bp = (const float4*)(b_ + 8 * part);
        float4 g0 = gp[0], g1 = gp[1];
        float4 bb0 = bp[0], bb1 = bp[1];
        float4 o0, o1;
        o0.x = (y[0] - mu) * rstd * g0.x + bb0.x;
        o0.y = (y[1] - mu) * rstd * g0.y + bb0.y;
        o0.z = (y[2] - mu) * rstd * g0.z + bb0.z;
        o0.w = (y[3] - mu) * rstd * g0.w + bb0.w;
        o1.x = (y[4] - mu) * rstd * g1.x + bb1.x;
        o1.y = (y[5] - mu) * rstd * g1.y + bb1.y;
        o1.z = (y[6] - mu) * rstd * g1.z + bb1.z;
        o1.w = (y[7] - mu) * rstd * g1.w + bb1.w;
        float4* xw = (float4*)(x + (size_t)v * DIM + 8 * part);
        xw[0] = o0; xw[1] = o1;
    }
}

// ---------------- decoder (fused): out = relu(x@W0+b0)@W1 + b1 ----------------

__global__ __launch_bounds__(256) void k_decM(const float* __restrict__ xi,
                                              const float* __restrict__ W0, const float* __restrict__ b0f,
                                              const float* __restrict__ W1, const float* __restrict__ b1f,
                                              float* __restrict__ out) {
    __shared__ short xs[32 * XS_STRIDE];
    int tid = threadIdx.x, lane = tid & 63, wv = tid >> 6;
    bfrag_t B0[2][4];
    load_bfrags<DIM, 2>(W0, 32 * wv, lane, B0);
    int q = lane >> 4, nn = lane & 15;
    bfrag_t B1[4];
    #pragma unroll
    for (int kc = 0; kc < 4; kc++) {
        int k0 = 32 * kc + 8 * q;
        bfrag_t f;
        #pragma unroll
        for (int j = 0; j < 8; j++)
            f[j] = (__bf16)W1[(size_t)(k0 + j) * DOUT + nn];
        B1[kc] = f;
    }
    float bias0[2] = { b0f[32 * wv + nn], b0f[32 * wv + 16 + nn] };
    float bias1 = b1f[nn];
    const int ngroups = N_NODES / 32;
    for (int g = blockIdx.x; g < ngroups; g += gridDim.x) {
        int n0 = g * 32;
        __syncthreads();
        stage_tile(xi + (size_t)n0 * DIM, xs, tid);
        __syncthreads();
        facc_t acc[2][2];
        #pragma unroll
        for (int mt = 0; mt < 2; mt++)
            #pragma unroll
            for (int nt = 0; nt < 2; nt++)
                acc[mt][nt] = (facc_t){bias0[nt], bias0[nt], bias0[nt], bias0[nt]};
        #pragma unroll
        for (int kc = 0; kc < 4; kc++) {
            bfrag_t a0 = *(const bfrag_t*)&xs[nn * XS_STRIDE + 32 * kc + 8 * q];
            bfrag_t a1 = *(const bfrag_t*)&xs[(16 + nn) * XS_STRIDE + 32 * kc + 8 * q];
            acc[0][0] = mfma16(a0, B0[0][kc], acc[0][0]);
            acc[0][1] = mfma16(a0, B0[1][kc], acc[0][1]);
            acc[1][0] = mfma16(a1, B0[0][kc], acc[1][0]);
            acc[1][1] = mfma16(a1, B0[1][kc], acc[1][1]);
        }
        __syncthreads();   // all A-reads of x-tile done; xs can be overwritten
        #pragma unroll
        for (int mt = 0; mt < 2; mt++)
            #pragma unroll
            for (int nt = 0; nt < 2; nt++)
                #pragma unroll
                for (int r = 0; r < 4; r++) {
                    int nl = 16 * mt + 4 * q + r;
                    int col = 32 * wv + 16 * nt + nn;
                    xs[nl * XS_STRIDE + col] = (short)f2bf(fmaxf(acc[mt][nt][r], 0.f));
                }
        __syncthreads();
        if (wv < 2) {   // waves 0,1: t2[32x128] @ W1[128x16]
            facc_t acc2 = (facc_t){bias1, bias1, bias1, bias1};
            #pragma unroll
            for (int kc = 0; kc < 4; kc++) {
                bfrag_t a = *(const bfrag_t*)&xs[(16 * wv + nn) * XS_STRIDE + 32 * kc + 8 * q];
                acc2 = mfma16(a, B1[kc], acc2);
            }
            #pragma unroll
            for (int r = 0; r < 4; r++) {
                int node = n0 + 16 * wv + 4 * q + r;
                out[(size_t)node * DOUT + nn] = acc2[r];
            }
        }
    }
}

// ---------------- launch ----------------

extern "C" void kernel_launch(void* const* d_in, const int* in_sizes, int n_in,
                              void* d_out, int out_size, void* d_ws, size_t ws_size,
                              hipStream_t stream) {
    const float* X      = (const float*)d_in[0];
    const float* W_enc0 = (const float*)d_in[1];
    const float* b_enc0 = (const float*)d_in[2];
    const float* W_enc1 = (const float*)d_in[3];
    const float* b_enc1 = (const float*)d_in[4];
    const float* W_conv = (const float*)d_in[5];
    const float* b_conv = (const float*)d_in[6];
    const float* ln_g   = (const float*)d_in[7];
    const float* ln_b   = (const float*)d_in[8];
    const float* W_dec0 = (const float*)d_in[9];
    const float* b_dec0 = (const float*)d_in[10];
    const float* W_dec1 = (const float*)d_in[11];
    const float* b_dec1 = (const float*)d_in[12];
    const int*   erow   = (const int*)d_in[13];         // edge_index[0] = sources
    const int*   ecol   = erow + NEDGE;                 // edge_index[1] = targets
    float* out = (float*)d_out;

    float*          x       = (float*)d_ws;                                  // N*128 f32
    unsigned short* hs      = (unsigned short*)(x + (size_t)N_NODES * DIM);  // N*128 bf16
    float*          dinv    = (float*)(hs + (size_t)N_NODES * DIM);          // N f32
    int*            indptr  = (int*)(dinv + N_NODES);                        // N+1 int
    int*            binsize = indptr + N_NODES + 8;                          // NBINS
    int*            binbase = binsize + NBINS + 8;                           // NBINS+1
    int*            bincur  = binbase + NBINS + 9;                           // NBINS
    int*            rows_s  = bincur + NBINS + 8;                            // E int
    unsigned*       pairs   = (unsigned*)hs;   // overlay: consumed before enc writes hs

    // CSR build (per launch; d_ws is re-poisoned before every call)
    k_zb     <<<1, 512, 0, stream>>>(binsize);
    k_hist   <<<NPB, 256, 0, stream>>>(ecol, binsize);
    k_scanb  <<<1, 512, 0, stream>>>(binsize, binbase, bincur);
    k_binpass<<<NPB, 256, 0, stream>>>(erow, ecol, bincur, pairs);
    k_csr2   <<<NBINS, 256, 0, stream>>>(pairs, binbase, indptr, dinv, rows_s);

    // encoder + conv step 1 fused
    k_encC<<<GGRID, 256, 0, stream>>>(X, W_enc0, b_enc0, W_enc1, b_enc1, W_conv, dinv, x, hs);

    // msg steps: lean gather kernel; conv for next step separate (GEMM-shaped)
    k_agg_ln<<<N_NODES / 4, 256, 0, stream>>>((const uint4*)hs, x, dinv, indptr, rows_s,
                                              b_conv, ln_g, ln_b);
    k_convM <<<GGRID, 256, 0, stream>>>(x, W_conv, dinv, hs);
    k_agg_ln<<<N_NODES / 4, 256, 0, stream>>>((const uint4*)hs, x, dinv, indptr, rows_s,
                                              b_conv, ln_g, ln_b);
    k_convM <<<GGRID, 256, 0, stream>>>(x, W_conv, dinv, hs);
    k_agg_ln<<<N_NODES / 4, 256, 0, stream>>>((const uint4*)hs, x, dinv, indptr, rows_s,
                                              b_conv, ln_g, ln_b);

    k_decM<<<GGRID, 256, 0, stream>>>(x, W_dec0, b_dec0, W_dec1, b_dec1, out);
}

// Round 9
// 600.882 us; speedup vs baseline: 1.1903x; 1.0650x over previous
//
#include <hip/hip_runtime.h>

#define N_NODES 100000
#define NEDGE   3200000
#define DIN     16
#define DIM     128
#define DOUT    16
#define LN_EPS  1e-5f
#define NBINS   391          // 256-target bins: bin = c >> 8
#define CHUNK   16384        // edges per chunk block
#define NPB     196          // ceil(NEDGE / CHUNK)
#define XS_STRIDE 136        // LDS bf16 row stride: 272B, 16B-aligned, 2-way-bank free
#define GGRID   1024         // GEMM grid

typedef __attribute__((ext_vector_type(8))) __bf16 bfrag_t;
typedef __attribute__((ext_vector_type(4))) float facc_t;

static __device__ __forceinline__ facc_t mfma16(bfrag_t a, bfrag_t b, facc_t c) {
    return __builtin_amdgcn_mfma_f32_16x16x32_bf16(a, b, c, 0, 0, 0);
}

// ---- bf16 helpers (RNE pack, cheap unpack) ----
static __device__ __forceinline__ unsigned f2bf(float f) {
    unsigned u = __float_as_uint(f);
    return (u + 0x7fffu + ((u >> 16) & 1u)) >> 16;
}
static __device__ __forceinline__ float bf_lo(unsigned u) { return __uint_as_float(u << 16); }
static __device__ __forceinline__ float bf_hi(unsigned u) { return __uint_as_float(u & 0xFFFF0000u); }

// ---------------- CSR build (no global per-node atomics) ----------------

__global__ __launch_bounds__(512) void k_zb(int* __restrict__ binsize) {
    if (threadIdx.x < NBINS) binsize[threadIdx.x] = 0;
}

__global__ __launch_bounds__(256) void k_hist(const int* __restrict__ col, int* __restrict__ binsize) {
    __shared__ int lh[NBINS];
    int tid = threadIdx.x;
    for (int b = tid; b < NBINS; b += 256) lh[b] = 0;
    __syncthreads();
    int e0 = blockIdx.x * CHUNK;
    int e1 = e0 + CHUNK; if (e1 > NEDGE) e1 = NEDGE;
    for (int e = e0 + tid; e < e1; e += 256)
        atomicAdd(&lh[col[e] >> 8], 1);
    __syncthreads();
    for (int b = tid; b < NBINS; b += 256)
        if (lh[b]) atomicAdd(&binsize[b], lh[b]);
}

__global__ __launch_bounds__(512) void k_scanb(const int* __restrict__ binsize,
                                               int* __restrict__ binbase, int* __restrict__ bincur) {
    __shared__ int sh[512];
    int t = threadIdx.x;
    int v = (t < NBINS) ? binsize[t] : 0;
    sh[t] = v;
    __syncthreads();
    for (int off = 1; off < 512; off <<= 1) {
        int a = (t >= off) ? sh[t - off] : 0;
        __syncthreads();
        sh[t] += a;
        __syncthreads();
    }
    if (t < NBINS) {
        int e = sh[t] - v;
        binbase[t] = e;
        bincur[t] = e;
    }
    if (t == 0) binbase[NBINS] = NEDGE;
}

__global__ __launch_bounds__(256) void k_binpass(const int* __restrict__ row, const int* __restrict__ col,
                                                 int* __restrict__ bincur, unsigned* __restrict__ pairs) {
    __shared__ int lhist[NBINS], lbase[NBINS], lofs[NBINS];
    int tid = threadIdx.x;
    for (int b = tid; b < NBINS; b += 256) { lhist[b] = 0; lofs[b] = 0; }
    __syncthreads();
    int e0 = blockIdx.x * CHUNK;
    int e1 = e0 + CHUNK; if (e1 > NEDGE) e1 = NEDGE;
    for (int e = e0 + tid; e < e1; e += 256)
        atomicAdd(&lhist[col[e] >> 8], 1);
    __syncthreads();
    for (int b = tid; b < NBINS; b += 256) {
        int h = lhist[b];
        lbase[b] = h ? atomicAdd(&bincur[b], h) : 0;
    }
    __syncthreads();
    for (int e = e0 + tid; e < e1; e += 256) {
        int c = col[e];
        int b = c >> 8;
        int pos = atomicAdd(&lofs[b], 1);
        pairs[lbase[b] + pos] = ((unsigned)(c & 255) << 17) | (unsigned)row[e];
    }
}

__global__ __launch_bounds__(256) void k_csr2(const unsigned* __restrict__ pairs,
                                              const int* __restrict__ binbase,
                                              int* __restrict__ indptr, float* __restrict__ dinv,
                                              int* __restrict__ rows_s) {
    __shared__ int lcnt[256], lptr[256], lofs[256];
    __shared__ int wsum[4];
    int tid = threadIdx.x;
    int b = blockIdx.x;
    int n0 = b << 8;
    int base = binbase[b], end = binbase[b + 1];
    lcnt[tid] = 0; lofs[tid] = 0;
    __syncthreads();
    for (int s = base + tid; s < end; s += 256)
        atomicAdd(&lcnt[pairs[s] >> 17], 1);
    __syncthreads();
    int v = lcnt[tid];
    int lane = tid & 63, w = tid >> 6;
    int s = v;
    for (int off = 1; off < 64; off <<= 1) {
        int t = __shfl_up(s, off);
        if (lane >= off) s += t;
    }
    if (lane == 63) wsum[w] = s;
    __syncthreads();
    int add = 0;
    for (int k = 0; k < w; k++) add += wsum[k];
    int excl = add + s - v;
    lptr[tid] = excl;
    int node = n0 + tid;
    if (node < N_NODES) {
        indptr[node] = base + excl;
        dinv[node] = rsqrtf((float)(v + 1));   // +1 self loop
    }
    if (b == NBINS - 1 && tid == 0) indptr[N_NODES] = NEDGE;
    __syncthreads();
    for (int s2 = base + tid; s2 < end; s2 += 256) {
        unsigned p = pairs[s2];
        int cl = p >> 17;
        int r  = p & 0x1FFFF;
        int dst = base + lptr[cl] + atomicAdd(&lofs[cl], 1);
        rows_s[dst] = r;
    }
}

// ---------------- MFMA helpers ----------------
template<int NC, int NT>
static __device__ __forceinline__ void load_bfrags(const float* __restrict__ W, int colbase,
                                                   int lane, bfrag_t B[NT][4]) {
    int q = lane >> 4, nn = lane & 15;
    #pragma unroll
    for (int nt = 0; nt < NT; nt++) {
        int col = colbase + 16 * nt + nn;
        #pragma unroll
        for (int kc = 0; kc < 4; kc++) {
            int k0 = 32 * kc + 8 * q;
            bfrag_t f;
            #pragma unroll
            for (int j = 0; j < 8; j++)
                f[j] = (__bf16)W[(size_t)(k0 + j) * NC + col];
            B[nt][kc] = f;
        }
    }
}

// stage 32 bf16 rows (256B each) -> LDS tile (stride XS_STRIDE), straight copy
static __device__ __forceinline__ void stage_bf(const unsigned short* __restrict__ src_base,
                                                short* __restrict__ xs, int tid) {
    int r = tid >> 3, s = tid & 7;   // 8 threads/row, 32B each
    const uint4* src = (const uint4*)(src_base + (size_t)r * DIM + 16 * s);
    uint4 a = src[0], b = src[1];
    *(uint4*)&xs[r * XS_STRIDE + 16 * s] = a;
    *(uint4*)&xs[r * XS_STRIDE + 16 * s + 8] = b;
}

// MFMA conv block: ys (32 rows bf16 in LDS) @ W-frags -> hs rows nb..nb+31, scaled by dinv
static __device__ __forceinline__ void conv_tail(const short* __restrict__ ys, bfrag_t B[2][4],
                                                 const float* __restrict__ dinv, int nb,
                                                 int lane, int wv, unsigned short* __restrict__ hs_out) {
    int q = lane >> 4, nn = lane & 15;
    facc_t a2[2][2] = {};
    #pragma unroll
    for (int kc = 0; kc < 4; kc++) {
        bfrag_t a0 = *(const bfrag_t*)&ys[nn * XS_STRIDE + 32 * kc + 8 * q];
        bfrag_t a1 = *(const bfrag_t*)&ys[(16 + nn) * XS_STRIDE + 32 * kc + 8 * q];
        a2[0][0] = mfma16(a0, B[0][kc], a2[0][0]);
        a2[0][1] = mfma16(a0, B[1][kc], a2[0][1]);
        a2[1][0] = mfma16(a1, B[0][kc], a2[1][0]);
        a2[1][1] = mfma16(a1, B[1][kc], a2[1][1]);
    }
    #pragma unroll
    for (int mt = 0; mt < 2; mt++)
        #pragma unroll
        for (int r = 0; r < 4; r++) {
            int node = nb + 16 * mt + 4 * q + r;
            float d = dinv[node];
            #pragma unroll
            for (int nt = 0; nt < 2; nt++)
                hs_out[(size_t)node * DIM + 32 * wv + 16 * nt + nn] =
                    (unsigned short)f2bf(a2[mt][nt][r] * d);
        }
}

// ---------------- encoder (fused): x_bf16 = relu(X@W0+b0)@W1+b1 ; hs = (x@Wc)*dinv ----------------

__global__ __launch_bounds__(256) void k_encC(const float* __restrict__ X,
                                              const float* __restrict__ W0, const float* __restrict__ b0,
                                              const float* __restrict__ W1, const float* __restrict__ b1,
                                              const float* __restrict__ Wc, const float* __restrict__ dinv,
                                              unsigned short* __restrict__ xo, unsigned short* __restrict__ hs_out) {
    __shared__ short xs[32 * XS_STRIDE];
    __shared__ float W0s[DIN * DIM];   // 8 KB
    __shared__ float b0s[DIM];
    int tid = threadIdx.x, lane = tid & 63, wv = tid >> 6;
    for (int i = tid; i < DIN * DIM / 4; i += 256) ((float4*)W0s)[i] = ((const float4*)W0)[i];
    if (tid < DIM) b0s[tid] = b0[tid];
    bfrag_t B[2][4];
    load_bfrags<DIM, 2>(W1, 32 * wv, lane, B);
    bfrag_t Bc[2][4];
    load_bfrags<DIM, 2>(Wc, 32 * wv, lane, Bc);
    int q = lane >> 4, nn = lane & 15;
    float bias[2] = { b1[32 * wv + nn], b1[32 * wv + 16 + nn] };
    const int ngroups = N_NODES / 32;
    for (int g = blockIdx.x; g < ngroups; g += gridDim.x) {
        int n0 = g * 32;
        __syncthreads();
        {   // stage: t = relu(X@W0+b0), node r, cols 16s..16s+15 -> bf16 LDS
            int r = tid >> 3, s = tid & 7;
            float xr[DIN];
            const float4* xsrc = (const float4*)(X + (size_t)(n0 + r) * DIN);
            #pragma unroll
            for (int i = 0; i < 4; i++) {
                float4 v = xsrc[i];
                xr[4*i] = v.x; xr[4*i+1] = v.y; xr[4*i+2] = v.z; xr[4*i+3] = v.w;
            }
            unsigned pk[8];
            #pragma unroll
            for (int cc = 0; cc < 16; cc += 2) {
                int c0 = 16 * s + cc;
                float a0 = b0s[c0], a1 = b0s[c0 + 1];
                #pragma unroll
                for (int k = 0; k < DIN; k++) {
                    float2 w = *(const float2*)&W0s[k * DIM + c0];
                    a0 += xr[k] * w.x; a1 += xr[k] * w.y;
                }
                pk[cc >> 1] = f2bf(fmaxf(a0, 0.f)) | (f2bf(fmaxf(a1, 0.f)) << 16);
            }
            *(uint4*)&xs[r * XS_STRIDE + 16 * s] = *(uint4*)&pk[0];
            *(uint4*)&xs[r * XS_STRIDE + 16 * s + 8] = *(uint4*)&pk[4];
        }
        __syncthreads();
        facc_t acc[2][2];
        #pragma unroll
        for (int mt = 0; mt < 2; mt++)
            #pragma unroll
            for (int nt = 0; nt < 2; nt++)
                acc[mt][nt] = (facc_t){bias[nt], bias[nt], bias[nt], bias[nt]};
        #pragma unroll
        for (int kc = 0; kc < 4; kc++) {
            bfrag_t a0 = *(const bfrag_t*)&xs[nn * XS_STRIDE + 32 * kc + 8 * q];
            bfrag_t a1 = *(const bfrag_t*)&xs[(16 + nn) * XS_STRIDE + 32 * kc + 8 * q];
            acc[0][0] = mfma16(a0, B[0][kc], acc[0][0]);
            acc[0][1] = mfma16(a0, B[1][kc], acc[0][1]);
            acc[1][0] = mfma16(a1, B[0][kc], acc[1][0]);
            acc[1][1] = mfma16(a1, B[1][kc], acc[1][1]);
        }
        // write x (bf16) and re-stage x tile as bf16 for the fused conv
        __syncthreads();   // all A-reads done; xs can be overwritten
        #pragma unroll
        for (int mt = 0; mt < 2; mt++)
            #pragma unroll
            for (int r = 0; r < 4; r++) {
                int node = n0 + 16 * mt + 4 * q + r;
                int nl = 16 * mt + 4 * q + r;
                #pragma unroll
                for (int nt = 0; nt < 2; nt++) {
                    int col = 32 * wv + 16 * nt + nn;
                    unsigned short bv = (unsigned short)f2bf(acc[mt][nt][r]);
                    xo[(size_t)node * DIM + col] = bv;
                    xs[nl * XS_STRIDE + col] = (short)bv;
                }
            }
        __syncthreads();
        conv_tail(xs, Bc, dinv, n0, lane, wv, hs_out);
    }
}

// ---------------- conv: hs_bf16 = (x_bf16 @ W_conv) * dinv[node] ----------------

__global__ __launch_bounds__(256) void k_convM(const unsigned short* __restrict__ xi,
                                               const float* __restrict__ W,
                                               const float* __restrict__ dinv,
                                               unsigned short* __restrict__ hs) {
    __shared__ short xs[32 * XS_STRIDE];
    int tid = threadIdx.x, lane = tid & 63, wv = tid >> 6;
    bfrag_t B[2][4];
    load_bfrags<DIM, 2>(W, 32 * wv, lane, B);
    const int ngroups = N_NODES / 32;
    for (int g = blockIdx.x; g < ngroups; g += gridDim.x) {
        int n0 = g * 32;
        __syncthreads();
        stage_bf(xi + (size_t)n0 * DIM, xs, tid);
        __syncthreads();
        conv_tail(xs, B, dinv, n0, lane, wv, hs);
    }
}

// ---------------- fused gather + residual + bias + LayerNorm (x stored bf16) ----------------
// one wave per node. dwordx4 gather: 16 lanes cover one 256B hs row => one load
// gathers 4 edges. sub = edge-in-group, part = 16B chunk (8 cols).

__global__ __launch_bounds__(256) void k_agg_ln(const uint4* __restrict__ hs4, uint4* __restrict__ x4,
                                                const float* __restrict__ dinv,
                                                const int* __restrict__ indptr,
                                                const int* __restrict__ rows_s,
                                                const float* __restrict__ bconv,
                                                const float* __restrict__ g_, const float* __restrict__ b_) {
    int v = (blockIdx.x * blockDim.x + threadIdx.x) >> 6;
    int lane = threadIdx.x & 63;
    if (v >= N_NODES) return;
    int sub = lane >> 4, part = lane & 15;
    float acc[8];
    {   // self loop: count once (sub 0 only; others init 0)
        uint4 u = hs4[(size_t)v * 16 + part];
        float sel = (sub == 0) ? 1.f : 0.f;
        acc[0] = sel * bf_lo(u.x); acc[1] = sel * bf_hi(u.x);
        acc[2] = sel * bf_lo(u.y); acc[3] = sel * bf_hi(u.y);
        acc[4] = sel * bf_lo(u.z); acc[5] = sel * bf_hi(u.z);
        acc[6] = sel * bf_lo(u.w); acc[7] = sel * bf_hi(u.w);
    }
    int beg = indptr[v], end = indptr[v + 1];
    for (int base = beg; base < end; base += 64) {
        int m = end - base; if (m > 64) m = 64;
        int r0 = rows_s[base + (lane < m ? lane : m - 1)];
        int k = 0;
        for (; k + 8 <= m; k += 8) {          // 2 loads in flight, 8 edges/iter
            int ra = __shfl(r0, k + sub);
            int rb = __shfl(r0, k + 4 + sub);
            uint4 ua = hs4[(size_t)ra * 16 + part];
            uint4 ub = hs4[(size_t)rb * 16 + part];
            acc[0] += bf_lo(ua.x); acc[1] += bf_hi(ua.x);
            acc[2] += bf_lo(ua.y); acc[3] += bf_hi(ua.y);
            acc[4] += bf_lo(ua.z); acc[5] += bf_hi(ua.z);
            acc[6] += bf_lo(ua.w); acc[7] += bf_hi(ua.w);
            acc[0] += bf_lo(ub.x); acc[1] += bf_hi(ub.x);
            acc[2] += bf_lo(ub.y); acc[3] += bf_hi(ub.y);
            acc[4] += bf_lo(ub.z); acc[5] += bf_hi(ub.z);
            acc[6] += bf_lo(ub.w); acc[7] += bf_hi(ub.w);
        }
        for (; k < m; k += 4) {               // predicated tail group
            int idx = k + sub;
            bool valid = idx < m;
            int r = __shfl(r0, valid ? idx : m - 1);
            uint4 u = hs4[(size_t)r * 16 + part];
            if (valid) {
                acc[0] += bf_lo(u.x); acc[1] += bf_hi(u.x);
                acc[2] += bf_lo(u.y); acc[3] += bf_hi(u.y);
                acc[4] += bf_lo(u.z); acc[5] += bf_hi(u.z);
                acc[6] += bf_lo(u.w); acc[7] += bf_hi(u.w);
            }
        }
    }
    #pragma unroll
    for (int j = 0; j < 8; j++) {             // sum the 4 sub-copies
        acc[j] += __shfl_xor(acc[j], 16);
        acc[j] += __shfl_xor(acc[j], 32);
    }
    float dv = dinv[v];
    float y[8];
    {
        uint4 xu = x4[(size_t)v * 16 + part];
        const float4* bc = (const float4*)(bconv + 8 * part);
        float4 b0 = bc[0], b1 = bc[1];
        y[0] = bf_lo(xu.x) + dv * acc[0] + b0.x; y[1] = bf_hi(xu.x) + dv * acc[1] + b0.y;
        y[2] = bf_lo(xu.y) + dv * acc[2] + b0.z; y[3] = bf_hi(xu.y) + dv * acc[3] + b0.w;
        y[4] = bf_lo(xu.z) + dv * acc[4] + b1.x; y[5] = bf_hi(xu.z) + dv * acc[5] + b1.y;
        y[6] = bf_lo(xu.w) + dv * acc[6] + b1.z; y[7] = bf_hi(xu.w) + dv * acc[7] + b1.w;
    }
    float s = 0.f, s2 = 0.f;
    #pragma unroll
    for (int j = 0; j < 8; j++) { s += y[j]; s2 += y[j] * y[j]; }
    #pragma unroll
    for (int off = 1; off < 16; off <<= 1) {  // reduce within 16-lane group (covers all parts)
        s += __shfl_xor(s, off);
        s2 += __shfl_xor(s2, off);
    }
    float mu = s * (1.f / 128.f);
    float rstd = rsqrtf(s2 * (1.f / 128.f) - mu * mu + LN_EPS);
    if (sub == 0) {
        const float4* gp = (const float4*)(g_ + 8 * part);
        const float4* bp = (const float4*)(b_ + 8 * part);
        float4 g0 = gp[0], g1 = gp[1];
        float4 bb0 = bp[0], bb1 = bp[1];
        float o[8];
        o[0] = (y[0] - mu) * rstd * g0.x + bb0.x;
        o[1] = (y[1] - mu) * rstd * g0.y + bb0.y;
        o[2] = (y[2] - mu) * rstd * g0.z + bb0.z;
        o[3] = (y[3] - mu) * rstd * g0.w + bb0.w;
        o[4] = (y[4] - mu) * rstd * g1.x + bb1.x;
        o[5] = (y[5] - mu) * rstd * g1.y + bb1.y;
        o[6] = (y[6] - mu) * rstd * g1.z + bb1.z;
        o[7] = (y[7] - mu) * rstd * g1.w + bb1.w;
        uint4 ow;
        ow.x = f2bf(o[0]) | (f2bf(o[1]) << 16);
        ow.y = f2bf(o[2]) | (f2bf(o[3]) << 16);
        ow.z = f2bf(o[4]) | (f2bf(o[5]) << 16);
        ow.w = f2bf(o[6]) | (f2bf(o[7]) << 16);
        x4[(size_t)v * 16 + part] = ow;
    }
}

// ---------------- decoder (fused): out = relu(x@W0+b0)@W1 + b1 ----------------

__global__ __launch_bounds__(256) void k_decM(const unsigned short* __restrict__ xi,
                                              const float* __restrict__ W0, const float* __restrict__ b0f,
                                              const float* __restrict__ W1, const float* __restrict__ b1f,
                                              float* __restrict__ out) {
    __shared__ short xs[32 * XS_STRIDE];
    int tid = threadIdx.x, lane = tid & 63, wv = tid >> 6;
    bfrag_t B0[2][4];
    load_bfrags<DIM, 2>(W0, 32 * wv, lane, B0);
    int q = lane >> 4, nn = lane & 15;
    bfrag_t B1[4];
    #pragma unroll
    for (int kc = 0; kc < 4; kc++) {
        int k0 = 32 * kc + 8 * q;
        bfrag_t f;
        #pragma unroll
        for (int j = 0; j < 8; j++)
            f[j] = (__bf16)W1[(size_t)(k0 + j) * DOUT + nn];
        B1[kc] = f;
    }
    float bias0[2] = { b0f[32 * wv + nn], b0f[32 * wv + 16 + nn] };
    float bias1 = b1f[nn];
    const int ngroups = N_NODES / 32;
    for (int g = blockIdx.x; g < ngroups; g += gridDim.x) {
        int n0 = g * 32;
        __syncthreads();
        stage_bf(xi + (size_t)n0 * DIM, xs, tid);
        __syncthreads();
        facc_t acc[2][2];
        #pragma unroll
        for (int mt = 0; mt < 2; mt++)
            #pragma unroll
            for (int nt = 0; nt < 2; nt++)
                acc[mt][nt] = (facc_t){bias0[nt], bias0[nt], bias0[nt], bias0[nt]};
        #pragma unroll
        for (int kc = 0; kc < 4; kc++) {
            bfrag_t a0 = *(const bfrag_t*)&xs[nn * XS_STRIDE + 32 * kc + 8 * q];
            bfrag_t a1 = *(const bfrag_t*)&xs[(16 + nn) * XS_STRIDE + 32 * kc + 8 * q];
            acc[0][0] = mfma16(a0, B0[0][kc], acc[0][0]);
            acc[0][1] = mfma16(a0, B0[1][kc], acc[0][1]);
            acc[1][0] = mfma16(a1, B0[0][kc], acc[1][0]);
            acc[1][1] = mfma16(a1, B0[1][kc], acc[1][1]);
        }
        __syncthreads();   // all A-reads of x-tile done; xs can be overwritten
        #pragma unroll
        for (int mt = 0; mt < 2; mt++)
            #pragma unroll
            for (int nt = 0; nt < 2; nt++)
                #pragma unroll
                for (int r = 0; r < 4; r++) {
                    int nl = 16 * mt + 4 * q + r;
                    int col = 32 * wv + 16 * nt + nn;
                    xs[nl * XS_STRIDE + col] = (short)f2bf(fmaxf(acc[mt][nt][r], 0.f));
                }
        __syncthreads();
        if (wv < 2) {   // waves 0,1: t2[32x128] @ W1[128x16]
            facc_t acc2 = (facc_t){bias1, bias1, bias1, bias1};
            #pragma unroll
            for (int kc = 0; kc < 4; kc++) {
                bfrag_t a = *(const bfrag_t*)&xs[(16 * wv + nn) * XS_STRIDE + 32 * kc + 8 * q];
                acc2 = mfma16(a, B1[kc], acc2);
            }
            #pragma unroll
            for (int r = 0; r < 4; r++) {
                int node = n0 + 16 * wv + 4 * q + r;
                out[(size_t)node * DOUT + nn] = acc2[r];
            }
        }
    }
}

// ---------------- launch ----------------

extern "C" void kernel_launch(void* const* d_in, const int* in_sizes, int n_in,
                              void* d_out, int out_size, void* d_ws, size_t ws_size,
                              hipStream_t stream) {
    const float* X      = (const float*)d_in[0];
    const float* W_enc0 = (const float*)d_in[1];
    const float* b_enc0 = (const float*)d_in[2];
    const float* W_enc1 = (const float*)d_in[3];
    const float* b_enc1 = (const float*)d_in[4];
    const float* W_conv = (const float*)d_in[5];
    const float* b_conv = (const float*)d_in[6];
    const float* ln_g   = (const float*)d_in[7];
    const float* ln_b   = (const float*)d_in[8];
    const float* W_dec0 = (const float*)d_in[9];
    const float* b_dec0 = (const float*)d_in[10];
    const float* W_dec1 = (const float*)d_in[11];
    const float* b_dec1 = (const float*)d_in[12];
    const int*   erow   = (const int*)d_in[13];         // edge_index[0] = sources
    const int*   ecol   = erow + NEDGE;                 // edge_index[1] = targets
    float* out = (float*)d_out;

    unsigned short* x       = (unsigned short*)d_ws;                         // N*128 bf16
    unsigned short* hs      = x + (size_t)N_NODES * DIM;                     // N*128 bf16
    float*          dinv    = (float*)(hs + (size_t)N_NODES * DIM);          // N f32
    int*            indptr  = (int*)(dinv + N_NODES);                        // N+1 int
    int*            binsize = indptr + N_NODES + 8;                          // NBINS
    int*            binbase = binsize + NBINS + 8;                           // NBINS+1
    int*            bincur  = binbase + NBINS + 9;                           // NBINS
    int*            rows_s  = bincur + NBINS + 8;                            // E int
    unsigned*       pairs   = (unsigned*)hs;   // overlay: consumed before enc writes hs

    // CSR build (per launch; d_ws is re-poisoned before every call)
    k_zb     <<<1, 512, 0, stream>>>(binsize);
    k_hist   <<<NPB, 256, 0, stream>>>(ecol, binsize);
    k_scanb  <<<1, 512, 0, stream>>>(binsize, binbase, bincur);
    k_binpass<<<NPB, 256, 0, stream>>>(erow, ecol, bincur, pairs);
    k_csr2   <<<NBINS, 256, 0, stream>>>(pairs, binbase, indptr, dinv, rows_s);

    // encoder + conv step 1 fused
    k_encC<<<GGRID, 256, 0, stream>>>(X, W_enc0, b_enc0, W_enc1, b_enc1, W_conv, dinv, x, hs);

    // msg steps: lean gather kernel; conv for next step separate (GEMM-shaped)
    k_agg_ln<<<N_NODES / 4, 256, 0, stream>>>((const uint4*)hs, (uint4*)x, dinv, indptr, rows_s,
                                              b_conv, ln_g, ln_b);
    k_convM <<<GGRID, 256, 0, stream>>>(x, W_conv, dinv, hs);
    k_agg_ln<<<N_NODES / 4, 256, 0, stream>>>((const uint4*)hs, (uint4*)x, dinv, indptr, rows_s,
                                              b_conv, ln_g, ln_b);
    k_convM <<<GGRID, 256, 0, stream>>>(x, W_conv, dinv, hs);
    k_agg_ln<<<N_NODES / 4, 256, 0, stream>>>((const uint4*)hs, (uint4*)x, dinv, indptr, rows_s,
                                              b_conv, ln_g, ln_b);

    k_decM<<<GGRID, 256, 0, stream>>>(x, W_dec0, b_dec0, W_dec1, b_dec1, out);
}

// Round 10
// 600.439 us; speedup vs baseline: 1.1912x; 1.0007x over previous
//
#include <hip/hip_runtime.h>

#define N_NODES 100000
#define NEDGE   3200000
#define DIN     16
#define DIM     128
#define DOUT    16
#define LN_EPS  1e-5f
#define NBINS   391          // 256-target bins: bin = c >> 8
#define CHUNK   16384        // edges per chunk block
#define NPB     196          // ceil(NEDGE / CHUNK)
#define XS_STRIDE 136        // LDS bf16 row stride: 272B, 16B-aligned, 2-way-bank free
#define GGRID   1024         // GEMM grid

typedef __attribute__((ext_vector_type(8))) __bf16 bfrag_t;
typedef __attribute__((ext_vector_type(4))) float facc_t;

static __device__ __forceinline__ facc_t mfma16(bfrag_t a, bfrag_t b, facc_t c) {
    return __builtin_amdgcn_mfma_f32_16x16x32_bf16(a, b, c, 0, 0, 0);
}

// ---- bf16 helpers (RNE pack, cheap unpack) ----
static __device__ __forceinline__ unsigned f2bf(float f) {
    unsigned u = __float_as_uint(f);
    return (u + 0x7fffu + ((u >> 16) & 1u)) >> 16;
}
static __device__ __forceinline__ float bf_lo(unsigned u) { return __uint_as_float(u << 16); }
static __device__ __forceinline__ float bf_hi(unsigned u) { return __uint_as_float(u & 0xFFFF0000u); }

// ---------------- CSR build: deterministic two-table partition ----------------
// pass 1: per-chunk histogram -> chunkhist[c][b] (plain stores, no atomics/zeroing)

__global__ __launch_bounds__(256) void k_hist2(const int* __restrict__ col,
                                               int* __restrict__ chunkhist) {
    __shared__ int lh[NBINS];
    int tid = threadIdx.x;
    for (int b = tid; b < NBINS; b += 256) lh[b] = 0;
    __syncthreads();
    int e0 = blockIdx.x * CHUNK;
    int e1 = e0 + CHUNK; if (e1 > NEDGE) e1 = NEDGE;
    for (int e = e0 + tid; e < e1; e += 256)
        atomicAdd(&lh[col[e] >> 8], 1);
    __syncthreads();
    int* out = chunkhist + (size_t)blockIdx.x * NBINS;
    for (int b = tid; b < NBINS; b += 256) out[b] = lh[b];
}

// pass 2 (1 block): bin totals -> bin scan -> binbase; per-(chunk,bin) bases
__global__ __launch_bounds__(512) void k_scan2(const int* __restrict__ chunkhist,
                                               int* __restrict__ binbase,
                                               int* __restrict__ chunkbase) {
    __shared__ int sh[512];
    int t = threadIdx.x;
    int tot = 0;
    if (t < NBINS)
        for (int c = 0; c < NPB; c++) tot += chunkhist[(size_t)c * NBINS + t];
    sh[t] = tot;
    __syncthreads();
    for (int off = 1; off < 512; off <<= 1) {
        int a = (t >= off) ? sh[t - off] : 0;
        __syncthreads();
        sh[t] += a;
        __syncthreads();
    }
    if (t < NBINS) {
        int excl = sh[t] - tot;
        binbase[t] = excl;
        int run = excl;
        for (int c = 0; c < NPB; c++) {
            chunkbase[(size_t)c * NBINS + t] = run;
            run += chunkhist[(size_t)c * NBINS + t];
        }
    }
    if (t == 0) binbase[NBINS] = NEDGE;
}

// pass 3: single sweep over edges; scatter packed pairs at precomputed bases
__global__ __launch_bounds__(256) void k_binpass2(const int* __restrict__ row, const int* __restrict__ col,
                                                  const int* __restrict__ chunkbase,
                                                  unsigned* __restrict__ pairs) {
    __shared__ int lbase[NBINS], lofs[NBINS];
    int tid = threadIdx.x;
    const int* cb = chunkbase + (size_t)blockIdx.x * NBINS;
    for (int b = tid; b < NBINS; b += 256) { lbase[b] = cb[b]; lofs[b] = 0; }
    __syncthreads();
    int e0 = blockIdx.x * CHUNK;
    int e1 = e0 + CHUNK; if (e1 > NEDGE) e1 = NEDGE;
    for (int e = e0 + tid; e < e1; e += 256) {
        int c = col[e];
        int b = c >> 8;
        int pos = atomicAdd(&lofs[b], 1);
        pairs[lbase[b] + pos] = ((unsigned)(c & 255) << 17) | (unsigned)row[e];
    }
}

// pass 4: one block per bin -> per-node counts, indptr, dinv, scatter rows_s
__global__ __launch_bounds__(256) void k_csr2(const unsigned* __restrict__ pairs,
                                              const int* __restrict__ binbase,
                                              int* __restrict__ indptr, float* __restrict__ dinv,
                                              int* __restrict__ rows_s) {
    __shared__ int lcnt[256], lptr[256], lofs[256];
    __shared__ int wsum[4];
    int tid = threadIdx.x;
    int b = blockIdx.x;
    int n0 = b << 8;
    int base = binbase[b], end = binbase[b + 1];
    lcnt[tid] = 0; lofs[tid] = 0;
    __syncthreads();
    for (int s = base + tid; s < end; s += 256)
        atomicAdd(&lcnt[pairs[s] >> 17], 1);
    __syncthreads();
    int v = lcnt[tid];
    int lane = tid & 63, w = tid >> 6;
    int s = v;
    for (int off = 1; off < 64; off <<= 1) {
        int t = __shfl_up(s, off);
        if (lane >= off) s += t;
    }
    if (lane == 63) wsum[w] = s;
    __syncthreads();
    int add = 0;
    for (int k = 0; k < w; k++) add += wsum[k];
    int excl = add + s - v;
    lptr[tid] = excl;
    int node = n0 + tid;
    if (node < N_NODES) {
        indptr[node] = base + excl;
        dinv[node] = rsqrtf((float)(v + 1));   // +1 self loop
    }
    if (b == NBINS - 1 && tid == 0) indptr[N_NODES] = NEDGE;
    __syncthreads();
    for (int s2 = base + tid; s2 < end; s2 += 256) {
        unsigned p = pairs[s2];
        int cl = p >> 17;
        int r  = p & 0x1FFFF;
        int dst = base + lptr[cl] + atomicAdd(&lofs[cl], 1);
        rows_s[dst] = r;
    }
}

// ---------------- MFMA helpers ----------------
template<int NC, int NT>
static __device__ __forceinline__ void load_bfrags(const float* __restrict__ W, int colbase,
                                                   int lane, bfrag_t B[NT][4]) {
    int q = lane >> 4, nn = lane & 15;
    #pragma unroll
    for (int nt = 0; nt < NT; nt++) {
        int col = colbase + 16 * nt + nn;
        #pragma unroll
        for (int kc = 0; kc < 4; kc++) {
            int k0 = 32 * kc + 8 * q;
            bfrag_t f;
            #pragma unroll
            for (int j = 0; j < 8; j++)
                f[j] = (__bf16)W[(size_t)(k0 + j) * NC + col];
            B[nt][kc] = f;
        }
    }
}

// stage 32 bf16 rows (256B each) -> LDS tile (stride XS_STRIDE), straight copy
static __device__ __forceinline__ void stage_bf(const unsigned short* __restrict__ src_base,
                                                short* __restrict__ xs, int tid) {
    int r = tid >> 3, s = tid & 7;   // 8 threads/row, 32B each
    const uint4* src = (const uint4*)(src_base + (size_t)r * DIM + 16 * s);
    uint4 a = src[0], b = src[1];
    *(uint4*)&xs[r * XS_STRIDE + 16 * s] = a;
    *(uint4*)&xs[r * XS_STRIDE + 16 * s + 8] = b;
}

// MFMA conv block: ys (32 rows bf16 in LDS) @ W-frags -> hs rows nb..nb+31, scaled by dinv
static __device__ __forceinline__ void conv_tail(const short* __restrict__ ys, bfrag_t B[2][4],
                                                 const float* __restrict__ dinv, int nb,
                                                 int lane, int wv, unsigned short* __restrict__ hs_out) {
    int q = lane >> 4, nn = lane & 15;
    facc_t a2[2][2] = {};
    #pragma unroll
    for (int kc = 0; kc < 4; kc++) {
        bfrag_t a0 = *(const bfrag_t*)&ys[nn * XS_STRIDE + 32 * kc + 8 * q];
        bfrag_t a1 = *(const bfrag_t*)&ys[(16 + nn) * XS_STRIDE + 32 * kc + 8 * q];
        a2[0][0] = mfma16(a0, B[0][kc], a2[0][0]);
        a2[0][1] = mfma16(a0, B[1][kc], a2[0][1]);
        a2[1][0] = mfma16(a1, B[0][kc], a2[1][0]);
        a2[1][1] = mfma16(a1, B[1][kc], a2[1][1]);
    }
    #pragma unroll
    for (int mt = 0; mt < 2; mt++)
        #pragma unroll
        for (int r = 0; r < 4; r++) {
            int node = nb + 16 * mt + 4 * q + r;
            float d = dinv[node];
            #pragma unroll
            for (int nt = 0; nt < 2; nt++)
                hs_out[(size_t)node * DIM + 32 * wv + 16 * nt + nn] =
                    (unsigned short)f2bf(a2[mt][nt][r] * d);
        }
}

// ---------------- encoder (fused): x_bf16 = relu(X@W0+b0)@W1+b1 ; hs = (x@Wc)*dinv ----------------

__global__ __launch_bounds__(256) void k_encC(const float* __restrict__ X,
                                              const float* __restrict__ W0, const float* __restrict__ b0,
                                              const float* __restrict__ W1, const float* __restrict__ b1,
                                              const float* __restrict__ Wc, const float* __restrict__ dinv,
                                              unsigned short* __restrict__ xo, unsigned short* __restrict__ hs_out) {
    __shared__ short xs[32 * XS_STRIDE];
    __shared__ float W0s[DIN * DIM];   // 8 KB
    __shared__ float b0s[DIM];
    int tid = threadIdx.x, lane = tid & 63, wv = tid >> 6;
    for (int i = tid; i < DIN * DIM / 4; i += 256) ((float4*)W0s)[i] = ((const float4*)W0)[i];
    if (tid < DIM) b0s[tid] = b0[tid];
    bfrag_t B[2][4];
    load_bfrags<DIM, 2>(W1, 32 * wv, lane, B);
    bfrag_t Bc[2][4];
    load_bfrags<DIM, 2>(Wc, 32 * wv, lane, Bc);
    int q = lane >> 4, nn = lane & 15;
    float bias[2] = { b1[32 * wv + nn], b1[32 * wv + 16 + nn] };
    const int ngroups = N_NODES / 32;
    for (int g = blockIdx.x; g < ngroups; g += gridDim.x) {
        int n0 = g * 32;
        __syncthreads();
        {   // stage: t = relu(X@W0+b0), node r, cols 16s..16s+15 -> bf16 LDS
            int r = tid >> 3, s = tid & 7;
            float xr[DIN];
            const float4* xsrc = (const float4*)(X + (size_t)(n0 + r) * DIN);
            #pragma unroll
            for (int i = 0; i < 4; i++) {
                float4 v = xsrc[i];
                xr[4*i] = v.x; xr[4*i+1] = v.y; xr[4*i+2] = v.z; xr[4*i+3] = v.w;
            }
            unsigned pk[8];
            #pragma unroll
            for (int cc = 0; cc < 16; cc += 2) {
                int c0 = 16 * s + cc;
                float a0 = b0s[c0], a1 = b0s[c0 + 1];
                #pragma unroll
                for (int k = 0; k < DIN; k++) {
                    float2 w = *(const float2*)&W0s[k * DIM + c0];
                    a0 += xr[k] * w.x; a1 += xr[k] * w.y;
                }
                pk[cc >> 1] = f2bf(fmaxf(a0, 0.f)) | (f2bf(fmaxf(a1, 0.f)) << 16);
            }
            *(uint4*)&xs[r * XS_STRIDE + 16 * s] = *(uint4*)&pk[0];
            *(uint4*)&xs[r * XS_STRIDE + 16 * s + 8] = *(uint4*)&pk[4];
        }
        __syncthreads();
        facc_t acc[2][2];
        #pragma unroll
        for (int mt = 0; mt < 2; mt++)
            #pragma unroll
            for (int nt = 0; nt < 2; nt++)
                acc[mt][nt] = (facc_t){bias[nt], bias[nt], bias[nt], bias[nt]};
        #pragma unroll
        for (int kc = 0; kc < 4; kc++) {
            bfrag_t a0 = *(const bfrag_t*)&xs[nn * XS_STRIDE + 32 * kc + 8 * q];
            bfrag_t a1 = *(const bfrag_t*)&xs[(16 + nn) * XS_STRIDE + 32 * kc + 8 * q];
            acc[0][0] = mfma16(a0, B[0][kc], acc[0][0]);
            acc[0][1] = mfma16(a0, B[1][kc], acc[0][1]);
            acc[1][0] = mfma16(a1, B[0][kc], acc[1][0]);
            acc[1][1] = mfma16(a1, B[1][kc], acc[1][1]);
        }
        // write x (bf16) and re-stage x tile as bf16 for the fused conv
        __syncthreads();   // all A-reads done; xs can be overwritten
        #pragma unroll
        for (int mt = 0; mt < 2; mt++)
            #pragma unroll
            for (int r = 0; r < 4; r++) {
                int node = n0 + 16 * mt + 4 * q + r;
                int nl = 16 * mt + 4 * q + r;
                #pragma unroll
                for (int nt = 0; nt < 2; nt++) {
                    int col = 32 * wv + 16 * nt + nn;
                    unsigned short bv = (unsigned short)f2bf(acc[mt][nt][r]);
                    xo[(size_t)node * DIM + col] = bv;
                    xs[nl * XS_STRIDE + col] = (short)bv;
                }
            }
        __syncthreads();
        conv_tail(xs, Bc, dinv, n0, lane, wv, hs_out);
    }
}

// ---------------- conv: hs_bf16 = (x_bf16 @ W_conv) * dinv[node] ----------------

__global__ __launch_bounds__(256) void k_convM(const unsigned short* __restrict__ xi,
                                               const float* __restrict__ W,
                                               const float* __restrict__ dinv,
                                               unsigned short* __restrict__ hs) {
    __shared__ short xs[32 * XS_STRIDE];
    int tid = threadIdx.x, lane = tid & 63, wv = tid >> 6;
    bfrag_t B[2][4];
    load_bfrags<DIM, 2>(W, 32 * wv, lane, B);
    const int ngroups = N_NODES / 32;
    for (int g = blockIdx.x; g < ngroups; g += gridDim.x) {
        int n0 = g * 32;
        __syncthreads();
        stage_bf(xi + (size_t)n0 * DIM, xs, tid);
        __syncthreads();
        conv_tail(xs, B, dinv, n0, lane, wv, hs);
    }
}

// ---------------- fused gather + residual + bias + LayerNorm (x stored bf16) ----------------

__global__ __launch_bounds__(256) void k_agg_ln(const uint4* __restrict__ hs4, uint4* __restrict__ x4,
                                                const float* __restrict__ dinv,
                                                const int* __restrict__ indptr,
                                                const int* __restrict__ rows_s,
                                                const float* __restrict__ bconv,
                                                const float* __restrict__ g_, const float* __restrict__ b_) {
    int v = (blockIdx.x * blockDim.x + threadIdx.x) >> 6;
    int lane = threadIdx.x & 63;
    if (v >= N_NODES) return;
    int sub = lane >> 4, part = lane & 15;
    float acc[8];
    {   // self loop: count once (sub 0 only; others init 0)
        uint4 u = hs4[(size_t)v * 16 + part];
        float sel = (sub == 0) ? 1.f : 0.f;
        acc[0] = sel * bf_lo(u.x); acc[1] = sel * bf_hi(u.x);
        acc[2] = sel * bf_lo(u.y); acc[3] = sel * bf_hi(u.y);
        acc[4] = sel * bf_lo(u.z); acc[5] = sel * bf_hi(u.z);
        acc[6] = sel * bf_lo(u.w); acc[7] = sel * bf_hi(u.w);
    }
    int beg = indptr[v], end = indptr[v + 1];
    for (int base = beg; base < end; base += 64) {
        int m = end - base; if (m > 64) m = 64;
        int r0 = rows_s[base + (lane < m ? lane : m - 1)];
        int k = 0;
        for (; k + 8 <= m; k += 8) {          // 2 loads in flight, 8 edges/iter
            int ra = __shfl(r0, k + sub);
            int rb = __shfl(r0, k + 4 + sub);
            uint4 ua = hs4[(size_t)ra * 16 + part];
            uint4 ub = hs4[(size_t)rb * 16 + part];
            acc[0] += bf_lo(ua.x); acc[1] += bf_hi(ua.x);
            acc[2] += bf_lo(ua.y); acc[3] += bf_hi(ua.y);
            acc[4] += bf_lo(ua.z); acc[5] += bf_hi(ua.z);
            acc[6] += bf_lo(ua.w); acc[7] += bf_hi(ua.w);
            acc[0] += bf_lo(ub.x); acc[1] += bf_hi(ub.x);
            acc[2] += bf_lo(ub.y); acc[3] += bf_hi(ub.y);
            acc[4] += bf_lo(ub.z); acc[5] += bf_hi(ub.z);
            acc[6] += bf_lo(ub.w); acc[7] += bf_hi(ub.w);
        }
        for (; k < m; k += 4) {               // predicated tail group
            int idx = k + sub;
            bool valid = idx < m;
            int r = __shfl(r0, valid ? idx : m - 1);
            uint4 u = hs4[(size_t)r * 16 + part];
            if (valid) {
                acc[0] += bf_lo(u.x); acc[1] += bf_hi(u.x);
                acc[2] += bf_lo(u.y); acc[3] += bf_hi(u.y);
                acc[4] += bf_lo(u.z); acc[5] += bf_hi(u.z);
                acc[6] += bf_lo(u.w); acc[7] += bf_hi(u.w);
            }
        }
    }
    #pragma unroll
    for (int j = 0; j < 8; j++) {             // sum the 4 sub-copies
        acc[j] += __shfl_xor(acc[j], 16);
        acc[j] += __shfl_xor(acc[j], 32);
    }
    float dv = dinv[v];
    float y[8];
    {
        uint4 xu = x4[(size_t)v * 16 + part];
        const float4* bc = (const float4*)(bconv + 8 * part);
        float4 b0 = bc[0], b1 = bc[1];
        y[0] = bf_lo(xu.x) + dv * acc[0] + b0.x; y[1] = bf_hi(xu.x) + dv * acc[1] + b0.y;
        y[2] = bf_lo(xu.y) + dv * acc[2] + b0.z; y[3] = bf_hi(xu.y) + dv * acc[3] + b0.w;
        y[4] = bf_lo(xu.z) + dv * acc[4] + b1.x; y[5] = bf_hi(xu.z) + dv * acc[5] + b1.y;
        y[6] = bf_lo(xu.w) + dv * acc[6] + b1.z; y[7] = bf_hi(xu.w) + dv * acc[7] + b1.w;
    }
    float s = 0.f, s2 = 0.f;
    #pragma unroll
    for (int j = 0; j < 8; j++) { s += y[j]; s2 += y[j] * y[j]; }
    #pragma unroll
    for (int off = 1; off < 16; off <<= 1) {  // reduce within 16-lane group (covers all parts)
        s += __shfl_xor(s, off);
        s2 += __shfl_xor(s2, off);
    }
    float mu = s * (1.f / 128.f);
    float rstd = rsqrtf(s2 * (1.f / 128.f) - mu * mu + LN_EPS);
    if (sub == 0) {
        const float4* gp = (const float4*)(g_ + 8 * part);
        const float4* bp = (const float4*)(b_ + 8 * part);
        float4 g0 = gp[0], g1 = gp[1];
        float4 bb0 = bp[0], bb1 = bp[1];
        float o[8];
        o[0] = (y[0] - mu) * rstd * g0.x + bb0.x;
        o[1] = (y[1] - mu) * rstd * g0.y + bb0.y;
        o[2] = (y[2] - mu) * rstd * g0.z + bb0.z;
        o[3] = (y[3] - mu) * rstd * g0.w + bb0.w;
        o[4] = (y[4] - mu) * rstd * g1.x + bb1.x;
        o[5] = (y[5] - mu) * rstd * g1.y + bb1.y;
        o[6] = (y[6] - mu) * rstd * g1.z + bb1.z;
        o[7] = (y[7] - mu) * rstd * g1.w + bb1.w;
        uint4 ow;
        ow.x = f2bf(o[0]) | (f2bf(o[1]) << 16);
        ow.y = f2bf(o[2]) | (f2bf(o[3]) << 16);
        ow.z = f2bf(o[4]) | (f2bf(o[5]) << 16);
        ow.w = f2bf(o[6]) | (f2bf(o[7]) << 16);
        x4[(size_t)v * 16 + part] = ow;
    }
}

// ---------------- decoder (fused): out = relu(x@W0+b0)@W1 + b1 ----------------

__global__ __launch_bounds__(256) void k_decM(const unsigned short* __restrict__ xi,
                                              const float* __restrict__ W0, const float* __restrict__ b0f,
                                              const float* __restrict__ W1, const float* __restrict__ b1f,
                                              float* __restrict__ out) {
    __shared__ short xs[32 * XS_STRIDE];
    int tid = threadIdx.x, lane = tid & 63, wv = tid >> 6;
    bfrag_t B0[2][4];
    load_bfrags<DIM, 2>(W0, 32 * wv, lane, B0);
    int q = lane >> 4, nn = lane & 15;
    bfrag_t B1[4];
    #pragma unroll
    for (int kc = 0; kc < 4; kc++) {
        int k0 = 32 * kc + 8 * q;
        bfrag_t f;
        #pragma unroll
        for (int j = 0; j < 8; j++)
            f[j] = (__bf16)W1[(size_t)(k0 + j) * DOUT + nn];
        B1[kc] = f;
    }
    float bias0[2] = { b0f[32 * wv + nn], b0f[32 * wv + 16 + nn] };
    float bias1 = b1f[nn];
    const int ngroups = N_NODES / 32;
    for (int g = blockIdx.x; g < ngroups; g += gridDim.x) {
        int n0 = g * 32;
        __syncthreads();
        stage_bf(xi + (size_t)n0 * DIM, xs, tid);
        __syncthreads();
        facc_t acc[2][2];
        #pragma unroll
        for (int mt = 0; mt < 2; mt++)
            #pragma unroll
            for (int nt = 0; nt < 2; nt++)
                acc[mt][nt] = (facc_t){bias0[nt], bias0[nt], bias0[nt], bias0[nt]};
        #pragma unroll
        for (int kc = 0; kc < 4; kc++) {
            bfrag_t a0 = *(const bfrag_t*)&xs[nn * XS_STRIDE + 32 * kc + 8 * q];
            bfrag_t a1 = *(const bfrag_t*)&xs[(16 + nn) * XS_STRIDE + 32 * kc + 8 * q];
            acc[0][0] = mfma16(a0, B0[0][kc], acc[0][0]);
            acc[0][1] = mfma16(a0, B0[1][kc], acc[0][1]);
            acc[1][0] = mfma16(a1, B0[0][kc], acc[1][0]);
            acc[1][1] = mfma16(a1, B0[1][kc], acc[1][1]);
        }
        __syncthreads();   // all A-reads of x-tile done; xs can be overwritten
        #pragma unroll
        for (int mt = 0; mt < 2; mt++)
            #pragma unroll
            for (int nt = 0; nt < 2; nt++)
                #pragma unroll
                for (int r = 0; r < 4; r++) {
                    int nl = 16 * mt + 4 * q + r;
                    int col = 32 * wv + 16 * nt + nn;
                    xs[nl * XS_STRIDE + col] = (short)f2bf(fmaxf(acc[mt][nt][r], 0.f));
                }
        __syncthreads();
        if (wv < 2) {   // waves 0,1: t2[32x128] @ W1[128x16]
            facc_t acc2 = (facc_t){bias1, bias1, bias1, bias1};
            #pragma unroll
            for (int kc = 0; kc < 4; kc++) {
                bfrag_t a = *(const bfrag_t*)&xs[(16 * wv + nn) * XS_STRIDE + 32 * kc + 8 * q];
                acc2 = mfma16(a, B1[kc], acc2);
            }
            #pragma unroll
            for (int r = 0; r < 4; r++) {
                int node = n0 + 16 * wv + 4 * q + r;
                out[(size_t)node * DOUT + nn] = acc2[r];
            }
        }
    }
}

// ---------------- launch ----------------

extern "C" void kernel_launch(void* const* d_in, const int* in_sizes, int n_in,
                              void* d_out, int out_size, void* d_ws, size_t ws_size,
                              hipStream_t stream) {
    const float* X      = (const float*)d_in[0];
    const float* W_enc0 = (const float*)d_in[1];
    const float* b_enc0 = (const float*)d_in[2];
    const float* W_enc1 = (const float*)d_in[3];
    const float* b_enc1 = (const float*)d_in[4];
    const float* W_conv = (const float*)d_in[5];
    const float* b_conv = (const float*)d_in[6];
    const float* ln_g   = (const float*)d_in[7];
    const float* ln_b   = (const float*)d_in[8];
    const float* W_dec0 = (const float*)d_in[9];
    const float* b_dec0 = (const float*)d_in[10];
    const float* W_dec1 = (const float*)d_in[11];
    const float* b_dec1 = (const float*)d_in[12];
    const int*   erow   = (const int*)d_in[13];         // edge_index[0] = sources
    const int*   ecol   = erow + NEDGE;                 // edge_index[1] = targets
    float* out = (float*)d_out;

    unsigned short* x         = (unsigned short*)d_ws;                       // N*128 bf16
    unsigned short* hs        = x + (size_t)N_NODES * DIM;                   // N*128 bf16
    float*          dinv      = (float*)(hs + (size_t)N_NODES * DIM);        // N f32
    int*            indptr    = (int*)(dinv + N_NODES);                      // N+1 int
    int*            binbase   = indptr + N_NODES + 8;                        // NBINS+1
    int*            chunkhist = binbase + NBINS + 9;                         // NPB*NBINS
    int*            chunkbase = chunkhist + NPB * NBINS + 8;                 // NPB*NBINS
    int*            rows_s    = chunkbase + NPB * NBINS + 8;                 // E int
    unsigned*       pairs     = (unsigned*)hs;   // overlay: consumed before enc writes hs

    // CSR build (per launch; d_ws is re-poisoned before every call)
    k_hist2   <<<NPB, 256, 0, stream>>>(ecol, chunkhist);
    k_scan2   <<<1, 512, 0, stream>>>(chunkhist, binbase, chunkbase);
    k_binpass2<<<NPB, 256, 0, stream>>>(erow, ecol, chunkbase, pairs);
    k_csr2    <<<NBINS, 256, 0, stream>>>(pairs, binbase, indptr, dinv, rows_s);

    // encoder + conv step 1 fused
    k_encC<<<GGRID, 256, 0, stream>>>(X, W_enc0, b_enc0, W_enc1, b_enc1, W_conv, dinv, x, hs);

    // msg steps: lean gather kernel; conv for next step separate (GEMM-shaped)
    k_agg_ln<<<N_NODES / 4, 256, 0, stream>>>((const uint4*)hs, (uint4*)x, dinv, indptr, rows_s,
                                              b_conv, ln_g, ln_b);
    k_convM <<<GGRID, 256, 0, stream>>>(x, W_conv, dinv, hs);
    k_agg_ln<<<N_NODES / 4, 256, 0, stream>>>((const uint4*)hs, (uint4*)x, dinv, indptr, rows_s,
                                              b_conv, ln_g, ln_b);
    k_convM <<<GGRID, 256, 0, stream>>>(x, W_conv, dinv, hs);
    k_agg_ln<<<N_NODES / 4, 256, 0, stream>>>((const uint4*)hs, (uint4*)x, dinv, indptr, rows_s,
                                              b_conv, ln_g, ln_b);

    k_decM<<<GGRID, 256, 0, stream>>>(x, W_dec0, b_dec0, W_dec1, b_dec1, out);
}